// Round 17
// baseline (577.115 us; speedup 1.0000x reference)
//
#include <hip/hip_runtime.h>
#include <math.h>

// RipsLayer: dim-0 persistence of Rips filtration on 4096 points in R^64.
// R17: merge fused into minedge via LAST-BLOCK ticket pattern (one atomic
// handoff, not a grid barrier — avoids R15's cooperative-sync cost):
//   256 blocks x 1024 thr scan D (one wave/row, shfl u64 reduce) and
//   atomicMin into best; __threadfence + ticket; the last block runs the
//   verified merge inline on 1024 threads (best read via device-scope
//   loads — all other blocks fenced before their ticket RMW), emits
//   edges, resets best, sets done, resets the ticket counter. Removes 12
//   merge dispatches (~70-90us of launch gaps + small-kernel time).
// build_d emits round-0 best (R16-verified). Replay = R16's Euler-tour
// rooting -> ANSV -> S -> r-major sort -> segscan -> doubling (verified).

#define N 4096
#define DF 64
#define INF __builtin_huge_valf()

__device__ __forceinline__ unsigned long long aload64(const unsigned long long* p) {
    return __hip_atomic_load(p, __ATOMIC_RELAXED, __HIP_MEMORY_SCOPE_AGENT);
}

// ---------------------------------------------------------------------------
// build_d + round-0 best (R16-verified).
// ---------------------------------------------------------------------------
__global__ __launch_bounds__(256) void build_d_kernel(const float* __restrict__ x,
                                                      float* __restrict__ D,
                                                      unsigned long long* __restrict__ best) {
    __shared__ float As[64][68];
    __shared__ float Bs[64][68];
    const int bi = blockIdx.y * 64;
    const int bj = blockIdx.x * 64;
    const int t = threadIdx.x;

#pragma unroll
    for (int g = 0; g < 4; ++g) {
        int idx = t + 256 * g;
        int row = idx >> 4;
        int k4 = (idx & 15) << 2;
        *(float4*)(&As[row][k4]) = *(const float4*)(x + (size_t)(bi + row) * DF + k4);
        *(float4*)(&Bs[row][k4]) = *(const float4*)(x + (size_t)(bj + row) * DF + k4);
    }
    __syncthreads();

    const int ti = (t >> 4) << 2;
    const int tj = (t & 15) << 2;
    float acc[4][4];
#pragma unroll
    for (int r = 0; r < 4; ++r)
#pragma unroll
        for (int c = 0; c < 4; ++c) acc[r][c] = 0.0f;

    for (int k = 0; k < 64; k += 4) {
        float4 a[4], b[4];
#pragma unroll
        for (int r = 0; r < 4; ++r) a[r] = *(const float4*)(&As[ti + r][k]);
#pragma unroll
        for (int c = 0; c < 4; ++c) b[c] = *(const float4*)(&Bs[tj + c][k]);
#pragma unroll
        for (int r = 0; r < 4; ++r)
#pragma unroll
            for (int c = 0; c < 4; ++c) {
                float d0 = a[r].x - b[c].x;
                float d1 = a[r].y - b[c].y;
                float d2 = a[r].z - b[c].z;
                float d3 = a[r].w - b[c].w;
                float s = acc[r][c];
                s = fmaf(d0, d0, s);
                s = fmaf(d1, d1, s);
                s = fmaf(d2, d2, s);
                s = fmaf(d3, d3, s);
                acc[r][c] = s;
            }
    }
#pragma unroll
    for (int r = 0; r < 4; ++r) {
        int i = bi + ti + r;
        float4 v;
        float* vp = &v.x;
        unsigned long long mk = ~0ULL;
#pragma unroll
        for (int c = 0; c < 4; ++c) {
            int j = bj + tj + c;
            vp[c] = (i == j) ? INF : sqrtf(fmaxf(acc[r][c], 1e-12f));
            unsigned long long key =
                ((unsigned long long)__float_as_uint(vp[c]) << 24) |
                ((unsigned long long)(unsigned)i << 12) | (unsigned)j;
            mk = key < mk ? key : mk;
        }
        *(float4*)(D + (size_t)i * N + (bj + tj)) = v;
#pragma unroll
        for (int m = 1; m < 16; m <<= 1) {
            unsigned long long o = __shfl_xor(mk, m, 64);
            mk = o < mk ? o : mk;
        }
        if ((t & 15) == 0) atomicMin(&best[i], mk);
    }
}

// ---------------------------------------------------------------------------
__global__ __launch_bounds__(256) void init_kernel(unsigned* comp,
                                                   unsigned long long* best,
                                                   unsigned* nedges, unsigned* done,
                                                   unsigned* counter) {
    int i = blockIdx.x * 256 + threadIdx.x;
    if (i < N) {
        comp[i] = (unsigned)i;
        best[i] = ~0ULL;
    }
    if (i == 0) { *nedges = 0u; *done = 0u; *counter = 0u; }
}

// ---------------------------------------------------------------------------
// Fused minedge + last-block merge. 256 blocks x 1024 threads.
// ---------------------------------------------------------------------------
__global__ __launch_bounds__(1024) void minedge_merge_kernel(
        const float* __restrict__ D, unsigned* comp, unsigned long long* best,
        unsigned long long* edges, unsigned* nedges, unsigned* done,
        unsigned* counter) {
    if (*done) return;
    __shared__ unsigned compc[N];  // 16 KB (pre-merge comp; scan + merge input)
    __shared__ unsigned np[N];     // 16 KB (merge scratch, last block only)
    __shared__ unsigned ticket_sh, cnt_sh;
    const int t = threadIdx.x;
    const int b = blockIdx.x;
    const int wv = t >> 6, lane = t & 63;

    for (int v = t; v < N; v += 1024) compc[v] = comp[v];
    __syncthreads();

    // ---- minedge scan: one wave per row ----
    {
        const int rowv = b * 16 + wv;
        const unsigned cr = compc[rowv];
        const float4* rowp = (const float4*)(D + (size_t)rowv * N);
        unsigned long long mykey = ~0ULL;
#pragma unroll 4
        for (int k = 0; k < 16; ++k) {
            float4 v4 = rowp[lane + 64 * k];
            int c0 = 4 * (lane + 64 * k);
            uint4 cc4 = *(const uint4*)&compc[c0];
            const float* vp = &v4.x;
            const unsigned* cp = &cc4.x;
#pragma unroll
            for (int q = 0; q < 4; ++q) {
                if (cp[q] != cr) {
                    unsigned long long key =
                        ((unsigned long long)__float_as_uint(vp[q]) << 24) |
                        ((unsigned long long)(unsigned)rowv << 12) |
                        (unsigned)(c0 + q);
                    mykey = key < mykey ? key : mykey;
                }
            }
        }
#pragma unroll
        for (int off = 32; off > 0; off >>= 1) {
            unsigned long long o = __shfl_down(mykey, (unsigned)off, 64);
            mykey = o < mykey ? o : mykey;
        }
        if (lane == 0 && mykey != ~0ULL) atomicMin(&best[cr], mykey);
    }
    __threadfence();  // publish atomicMins before taking the ticket
    __syncthreads();
    if (t == 0) ticket_sh = atomicAdd(counter, 1u);
    __syncthreads();
    if (ticket_sh != 255u) return;

    // ---- last block: merge (verified R14 logic, 1024 threads) ----
    if (t == 0) *counter = 0u;  // reset for next round
    unsigned long long kreg[4];
#pragma unroll
    for (int i = 0; i < 4; ++i) {
        int v = t + 1024 * i;
        unsigned p;
        unsigned long long k = ~0ULL;
        if (compc[v] == (unsigned)v) {
            k = aload64(&best[v]);
            p = (k != ~0ULL) ? compc[(unsigned)(k & 0xFFFu)] : (unsigned)v;
        } else {
            p = compc[v];
        }
        np[v] = p;
        kreg[i] = k;
    }
    __syncthreads();
#pragma unroll
    for (int i = 0; i < 4; ++i) {
        int v = t + 1024 * i;
        if (compc[v] == (unsigned)v) {
            unsigned p = np[v];
            if (p != (unsigned)v) {
                bool mutual = (np[p] == (unsigned)v);
                if (mutual && (unsigned)v < p) {
                    np[v] = (unsigned)v;
                } else {
                    unsigned idx = atomicAdd(nedges, 1u);
                    edges[idx] = kreg[i];
                }
            }
        }
    }
    __syncthreads();
    for (int it = 0; it < 12; ++it) {
#pragma unroll
        for (int i = 0; i < 4; ++i) {
            int v = t + 1024 * i;
            np[v] = np[np[v]];  // monotone; benign race (R8-verified)
        }
        __syncthreads();
    }
    if (t == 0) cnt_sh = 0u;
    __syncthreads();
    unsigned local = 0;
#pragma unroll
    for (int i = 0; i < 4; ++i) {
        int v = t + 1024 * i;
        unsigned r2 = np[v];
        comp[v] = r2;
        best[v] = ~0ULL;
        if (r2 == (unsigned)v) ++local;
    }
    atomicAdd(&cnt_sh, local);
    __syncthreads();
    if (t == 0 && cnt_sh == 1u) *done = 1u;
}

// ---------------------------------------------------------------------------
// Fallback recompute minedge + merge (R13-verified) for small ws.
// ---------------------------------------------------------------------------
__global__ __launch_bounds__(256) void minedge_kernel(const float* __restrict__ x,
                                                      const unsigned* __restrict__ comp,
                                                      unsigned long long* __restrict__ best,
                                                      const unsigned* __restrict__ done) {
    if (*done) return;
    __shared__ float xr[16][64];
    __shared__ float xc[64][68];
    __shared__ unsigned compr[16];
    __shared__ unsigned compc[64];
    __shared__ unsigned long long keybuf[256];
    const int t = threadIdx.x;
    const int b = blockIdx.x;
    const int r = t >> 4;
    const int rowv = b * 16 + r;

    {
        int row = t >> 4, f4 = t & 15;
        *(float4*)&xr[row][f4 * 4] =
            *(const float4*)(x + (size_t)(b * 16 + row) * DF + f4 * 4);
        if (t < 16) compr[t] = comp[b * 16 + t];
    }
    __syncthreads();
    const unsigned cr = compr[r];
    unsigned long long mykey = ~0ULL;

    for (int tile = 0; tile < 64; ++tile) {
        {
#pragma unroll
            for (int q = 0; q < 4; ++q) {
                int idx = t + 256 * q;
                int col = idx >> 4, k4 = (idx & 15) * 4;
                *(float4*)&xc[col][k4] =
                    *(const float4*)(x + (size_t)(tile * 64 + col) * DF + k4);
            }
            if (t < 64) compc[t] = comp[tile * 64 + t];
        }
        __syncthreads();
#pragma unroll
        for (int q = 0; q < 4; ++q) {
            int c = (t & 15) + 16 * q;
            unsigned cc = compc[c];
            if (cc != cr) {
                float s = 0.0f;
#pragma unroll
                for (int k = 0; k < 64; k += 4) {
                    float4 a = *(const float4*)&xr[r][k];
                    float4 bb = *(const float4*)&xc[c][k];
                    float d0 = a.x - bb.x;
                    float d1 = a.y - bb.y;
                    float d2 = a.z - bb.z;
                    float d3 = a.w - bb.w;
                    s = fmaf(d0, d0, s);
                    s = fmaf(d1, d1, s);
                    s = fmaf(d2, d2, s);
                    s = fmaf(d3, d3, s);
                }
                float w = sqrtf(fmaxf(s, 1e-12f));
                unsigned long long key =
                    ((unsigned long long)__float_as_uint(w) << 24) |
                    ((unsigned long long)(unsigned)rowv << 12) |
                    (unsigned)(tile * 64 + c);
                mykey = key < mykey ? key : mykey;
            }
        }
        __syncthreads();
    }
    keybuf[t] = mykey;
    __syncthreads();
    if (t < 16) {
        unsigned long long k = ~0ULL;
#pragma unroll
        for (int i = 0; i < 16; ++i) {
            unsigned long long v2 = keybuf[t * 16 + i];
            k = v2 < k ? v2 : k;
        }
        if (k != ~0ULL) atomicMin(&best[compr[t]], k);
    }
}

__global__ void merge_kernel(unsigned* comp, unsigned long long* best,
                             unsigned long long* edges, unsigned* nedges,
                             unsigned* done) {
    if (*done) return;
    __shared__ unsigned cl[N];
    __shared__ unsigned np[N];
    __shared__ unsigned cnt;
    const int t = threadIdx.x;
    const int bs = blockDim.x;
    for (int v = t; v < N; v += bs) cl[v] = comp[v];
    __syncthreads();
    for (int v = t; v < N; v += bs) {
        unsigned p;
        if (cl[v] == (unsigned)v) {
            unsigned long long k = best[v];
            p = (k != ~0ULL) ? cl[(unsigned)(k & 0xFFFu)] : (unsigned)v;
        } else {
            p = cl[v];
        }
        np[v] = p;
    }
    __syncthreads();
    for (int v = t; v < N; v += bs) {
        if (cl[v] == (unsigned)v) {
            unsigned p = np[v];
            if (p != (unsigned)v) {
                bool mutual = (np[p] == (unsigned)v);
                if (mutual && (unsigned)v < p) {
                    np[v] = (unsigned)v;
                } else {
                    unsigned idx = atomicAdd(nedges, 1u);
                    edges[idx] = best[v];
                }
            }
        }
    }
    __syncthreads();
    for (int it = 0; it < 12; ++it) {
        for (int v = t; v < N; v += bs) np[v] = np[np[v]];
        __syncthreads();
    }
    if (t == 0) cnt = 0;
    __syncthreads();
    unsigned local = 0;
    for (int v = t; v < N; v += bs) {
        comp[v] = np[v];
        best[v] = ~0ULL;
        if (np[v] == (unsigned)v) ++local;
    }
    atomicAdd(&cnt, local);
    __syncthreads();
    if (t == 0 && cnt == 1u) *done = 1u;
}

// ---------------------------------------------------------------------------
// Replay (R16-verified): CSR(+twin) -> Euler-tour list-ranking -> ANSV ->
// S -> r-major sort -> segmented scan -> pointer-doubling -> scatter.
// ---------------------------------------------------------------------------
__global__ __launch_bounds__(1024) void replay_kernel(
        const unsigned long long* __restrict__ edges,
        const unsigned* __restrict__ nedges, float* __restrict__ out) {
    __shared__ __align__(16) unsigned char pool[156680];
    __shared__ unsigned chg;
    unsigned* off = (unsigned*)(pool + 65536);
    unsigned long long* ent = (unsigned long long*)(pool + 0);
    unsigned short* par = (unsigned short*)(pool + 81928);
    unsigned* keyw = (unsigned*)(pool + 90120);
    unsigned long long* key64 = (unsigned long long*)(pool + 0);
    unsigned long long* order = (unsigned long long*)(pool + 0);
    unsigned* ptr = (unsigned*)(pool + 106504);
    unsigned short* rankA = (unsigned short*)(pool + 106504);
    unsigned short* nxtA = (unsigned short*)(pool + 122888);
    unsigned short* twin = (unsigned short*)(pool + 139272);
    unsigned* Sa = (unsigned*)(pool + 32768);
    unsigned* Sb = (unsigned*)(pool + 49152);
    unsigned* T = (unsigned*)(pool + 65536);
    unsigned* vA = (unsigned*)(pool + 122888);
    unsigned* jA = (unsigned*)(pool + 139272);
    unsigned* vB = (unsigned*)(pool + 0);
    unsigned* jB = (unsigned*)(pool + 16384);
    unsigned* csum = (unsigned*)(pool + 155656);
    const int t = threadIdx.x;
    const unsigned ne = *nedges;
    const int ns = 2 * (int)ne;

    for (int v = t; v < N; v += 1024) off[v] = 0u;
    if (t == 0) off[N] = 0u;
    for (int k = t; k < N - 1; k += 1024) out[2 * k] = 0.0f;
    __syncthreads();
    for (int e = t; e < (int)ne; e += 1024) {
        unsigned long long k = edges[e];
        atomicAdd(&off[(unsigned)(k >> 12) & 0xFFFu], 1u);
        atomicAdd(&off[(unsigned)k & 0xFFFu], 1u);
    }
    __syncthreads();
    unsigned sloc = 0;
    unsigned loc[16];
    if (t < 256) {
        int base = t * 16;
#pragma unroll
        for (int i = 0; i < 16; ++i) {
            unsigned d = off[base + i];
            loc[i] = sloc;
            sloc += d;
        }
        csum[t] = sloc;
    }
    __syncthreads();
    for (int d = 1; d < 256; d <<= 1) {
        unsigned addv = 0;
        if (t < 256 && t >= d) addv = csum[t - d];
        __syncthreads();
        if (t < 256) csum[t] += addv;
        __syncthreads();
    }
    if (t < 256) {
        int base = t * 16;
        unsigned excl = csum[t] - sloc;
#pragma unroll
        for (int i = 0; i < 16; ++i) {
            unsigned o = loc[i] + excl;
            off[base + i] = o;
            keyw[base + i] = o;
        }
        if (t == 255) off[N] = csum[255];
    }
    __syncthreads();
    for (int e = t; e < (int)ne; e += 1024) {
        unsigned long long k = edges[e];
        unsigned a = (unsigned)(k >> 12) & 0xFFFu;
        unsigned b = (unsigned)k & 0xFFFu;
        unsigned long long wb = k >> 24;
        unsigned p1 = atomicAdd(&keyw[a], 1u);
        unsigned p2 = atomicAdd(&keyw[b], 1u);
        ent[p1] = (wb << 12) | b;
        ent[p2] = (wb << 12) | a;
        twin[p1] = (unsigned short)p2;
        twin[p2] = (unsigned short)p1;
    }
    __syncthreads();
    const unsigned s0 = off[0];
    for (int s = t; s < ns; s += 1024) {
        unsigned v = (unsigned)ent[s] & 0xFFFu;
        unsigned t2 = twin[s];
        unsigned nx = t2 + 1u;
        if (nx == off[v + 1]) nx = off[v];
        if (nx == s0) nx = 0xFFFFu;
        nxtA[s] = (unsigned short)nx;
        rankA[s] = 1;
    }
    __syncthreads();
    for (int round = 0; round < 13; ++round) {
        unsigned short rr[8], nn[8];
#pragma unroll
        for (int q = 0; q < 8; ++q) {
            int s = t + 1024 * q;
            rr[q] = 0;
            nn[q] = 0xFFFFu;
            if (s < ns) {
                unsigned n2 = nxtA[s];
                if (n2 != 0xFFFFu) {
                    rr[q] = rankA[n2];
                    nn[q] = nxtA[n2];
                }
            }
        }
        __syncthreads();
#pragma unroll
        for (int q = 0; q < 8; ++q) {
            int s = t + 1024 * q;
            if (s < ns && nxtA[s] != 0xFFFFu) {
                rankA[s] = (unsigned short)(rankA[s] + rr[q]);
                nxtA[s] = nn[q];
            }
        }
        __syncthreads();
    }
    for (int s = t; s < ns; s += 1024) {
        unsigned t2 = twin[s];
        if (rankA[s] > rankA[t2]) {
            unsigned v = (unsigned)ent[s] & 0xFFFu;
            par[v] = (unsigned short)((unsigned)ent[t2] & 0xFFFu);
            keyw[v] = (unsigned)(ent[s] >> 12);
        }
    }
    if (t == 0) {
        par[0] = 0;
        chg = 0u;
    }
    __syncthreads();
    for (int v = t; v < N; v += 1024) {
        key64[v] = (v == 0) ? ~0ULL
                            : (((unsigned long long)keyw[v]) << 24) |
                                  ((unsigned long long)par[v] << 12) | (unsigned)v;
    }
    __syncthreads();
    for (int v = t; v < N; v += 1024) ptr[v] = (v == 0) ? 0u : (unsigned)par[v];
    __syncthreads();
    for (;;) {
        for (int v = t; v < N; v += 1024) {
            unsigned p = ptr[v];
            if (key64[p] <= key64[v]) {
                unsigned q = ptr[p];
                if (q != p) {
                    ptr[v] = q;
                    chg = 1u;
                }
            }
        }
        __syncthreads();
        unsigned fin = (chg == 0u);
        __syncthreads();
        if (t == 0) chg = 0u;
        __syncthreads();
        if (fin) break;
    }
    unsigned* Sc = Sa;
    unsigned* Sn = Sb;
    for (int v = t; v < N; v += 1024) Sc[v] = 1u;
    __syncthreads();
    for (int round = 0; round < 64; ++round) {
        for (int v = t; v < N; v += 1024) Sn[v] = 1u;
        __syncthreads();
        for (int v = t; v < N; v += 1024)
            if (v != 0) atomicAdd(&Sn[ptr[v]], Sc[v]);
        __syncthreads();
        for (int v = t; v < N; v += 1024)
            if (Sn[v] != Sc[v]) chg = 1u;
        __syncthreads();
        unsigned fin = (chg == 0u);
        __syncthreads();
        if (t == 0) chg = 0u;
        __syncthreads();
        unsigned* tmp = Sc; Sc = Sn; Sn = tmp;
        if (fin) break;
    }
    for (int v = t; v < N; v += 1024) {
        order[v] = (v == 0)
                       ? (0xFFFFFull << 44)
                       : (((unsigned long long)ptr[v]) << 44) |
                             (((unsigned long long)keyw[v]) << 12) | (unsigned)v;
    }
    __syncthreads();
    for (unsigned k = 2; k <= 4096; k <<= 1) {
        for (unsigned j = k >> 1; j > 0; j >>= 1) {
            for (unsigned i = t; i < 4096; i += 1024) {
                unsigned p = i ^ j;
                if (p > i) {
                    unsigned long long a = order[i], b = order[p];
                    bool up = ((i & k) == 0);
                    if ((a > b) == up) {
                        order[i] = b;
                        order[p] = a;
                    }
                }
            }
            __syncthreads();
        }
    }
    for (int i = t; i < 4096; i += 1024) {
        unsigned vv = (unsigned)order[i] & 0xFFFu;
        T[i] = Sc[vv];
    }
    __syncthreads();
    for (int d = 1; d < 4096; d <<= 1) {
        unsigned addv[4];
#pragma unroll
        for (int q = 0; q < 4; ++q) {
            int i = t + 1024 * q;
            addv[q] = 0;
            if (i >= d && (order[i] >> 44) == (order[i - d] >> 44)) addv[q] = T[i - d];
        }
        __syncthreads();
#pragma unroll
        for (int q = 0; q < 4; ++q) T[t + 1024 * q] += addv[q];
        __syncthreads();
    }
    for (int i = t; i < 4096; i += 1024) {
        unsigned vv = (unsigned)order[i] & 0xFFFu;
        if (vv) {
            vA[vv] = 1u + T[i] - Sc[vv];
            jA[vv] = ptr[vv];
        }
    }
    if (t == 0) {
        vA[0] = 0u;
        jA[0] = 0u;
    }
    __syncthreads();
    {
        unsigned *va = vA, *vb = vB, *ja = jA, *jb = jB;
        for (int r = 0; r < 12; ++r) {
            for (int v = t; v < N; v += 1024) {
                unsigned j2 = ja[v];
                vb[v] = va[v] + va[j2];
                jb[v] = ja[j2];
            }
            __syncthreads();
            unsigned* tmp;
            tmp = va; va = vb; vb = tmp;
            tmp = ja; ja = jb; jb = tmp;
        }
        for (int v = t; v < N; v += 1024) {
            if (v) out[2 * (va[v] - 1) + 1] = __uint_as_float(keyw[v]);
        }
    }
}

// ---------------------------------------------------------------------------
extern "C" void kernel_launch(void* const* d_in, const int* in_sizes, int n_in,
                              void* d_out, int out_size, void* d_ws, size_t ws_size,
                              hipStream_t stream) {
    const float* x = (const float*)d_in[0];
    float* out = (float*)d_out;  // [N-1][2]: (birth=0, death)
    const size_t dbytes = (size_t)N * N * 4;

    if (ws_size >= dbytes + 90112) {
        float* D = (float*)d_ws;
        unsigned char* st = (unsigned char*)d_ws + dbytes;
        unsigned long long* best = (unsigned long long*)st;            // 32 KB
        unsigned* comp = (unsigned*)(st + 32768);                      // 16 KB
        unsigned long long* edges = (unsigned long long*)(st + 49152); // 32760 B
        unsigned* nedges = (unsigned*)(st + 81912);
        unsigned* done = (unsigned*)(st + 81916);
        unsigned* counter = (unsigned*)(st + 81920);

        dim3 grid(N / 64, N / 64);
        init_kernel<<<16, 256, 0, stream>>>(comp, best, nedges, done, counter);
        build_d_kernel<<<grid, 256, 0, stream>>>(x, D, best);  // emits round-0 best
        merge_kernel<<<1, 1024, 0, stream>>>(comp, best, edges, nedges, done);
        for (int r = 1; r < 12; ++r) {
            minedge_merge_kernel<<<256, 1024, 0, stream>>>(D, comp, best, edges,
                                                           nedges, done, counter);
        }
        replay_kernel<<<1, 1024, 0, stream>>>(edges, nedges, out);
    } else {
        // Recompute fallback (R13-verified structure).
        unsigned char* ws = (unsigned char*)d_ws;
        unsigned* comp = (unsigned*)ws;                                  // 16 KB
        unsigned long long* best = (unsigned long long*)(ws + 16384);    // 32 KB
        unsigned long long* edges = (unsigned long long*)(ws + 49152);   // 32 KB
        unsigned* nedges = (unsigned*)(ws + 81920);
        unsigned* done = (unsigned*)(ws + 81984);

        init_kernel<<<16, 256, 0, stream>>>(comp, best, nedges, done,
                                            (unsigned*)(ws + 81988));
        for (int r = 0; r < 12; ++r) {
            minedge_kernel<<<256, 256, 0, stream>>>(x, comp, best, done);
            merge_kernel<<<1, 1024, 0, stream>>>(comp, best, edges, nedges, done);
        }
        replay_kernel<<<1, 1024, 0, stream>>>(edges, nedges, out);
    }
}

// Round 18
// 486.381 us; speedup vs baseline: 1.1865x; 1.1865x over previous
//
#include <hip/hip_runtime.h>
#include <math.h>

// RipsLayer: dim-0 persistence of Rips filtration on 4096 points in R^64.
// R18 = REVERT to R16 (verified 491us), the best-known structure:
//   - build_d materializes D (64 MiB, L2/L3-resident) AND emits round-0
//     Boruvka best (singleton comps -> per-row min, shfl_xor u64 reduce).
//   - Boruvka rounds as SPLIT small kernels (minedge_d 256thr / merge
//     1024thr). R15 (cooperative fusion, +55%) and R17 (last-block ticket
//     fusion, +18%) both proved fusion LOSES on this chip: launch gaps
//     are only ~2-4us while fused variants pay threadfence/L2-writeback,
//     grid-sync, or duplicated-merge costs.
//   - replay: CSR(+twin) -> Euler-tour list-ranking rooting (depth-
//     independent) -> ANSV (monotone pointer jumping) -> subtree sizes S
//     (child-sum iteration) -> r-major bitonic sort -> segmented scan
//     (vA) -> pointer-doubling rank -> scatter. All phases verified
//     (absmax 0.0 in R10/R12/R13/R14/R16).

#define N 4096
#define DF 64
#define INF __builtin_huge_valf()

// ---------------------------------------------------------------------------
// build_d + round-0 best: D[i][j] = sqrt(max(|xi-xj|^2,1e-12)), diag=+inf;
// per-row min key atomicMin'd into best[row] (round-0 comps are singletons).
// ---------------------------------------------------------------------------
__global__ __launch_bounds__(256) void build_d_kernel(const float* __restrict__ x,
                                                      float* __restrict__ D,
                                                      unsigned long long* __restrict__ best) {
    __shared__ float As[64][68];
    __shared__ float Bs[64][68];
    const int bi = blockIdx.y * 64;
    const int bj = blockIdx.x * 64;
    const int t = threadIdx.x;

#pragma unroll
    for (int g = 0; g < 4; ++g) {
        int idx = t + 256 * g;
        int row = idx >> 4;
        int k4 = (idx & 15) << 2;
        *(float4*)(&As[row][k4]) = *(const float4*)(x + (size_t)(bi + row) * DF + k4);
        *(float4*)(&Bs[row][k4]) = *(const float4*)(x + (size_t)(bj + row) * DF + k4);
    }
    __syncthreads();

    const int ti = (t >> 4) << 2;
    const int tj = (t & 15) << 2;
    float acc[4][4];
#pragma unroll
    for (int r = 0; r < 4; ++r)
#pragma unroll
        for (int c = 0; c < 4; ++c) acc[r][c] = 0.0f;

    for (int k = 0; k < 64; k += 4) {
        float4 a[4], b[4];
#pragma unroll
        for (int r = 0; r < 4; ++r) a[r] = *(const float4*)(&As[ti + r][k]);
#pragma unroll
        for (int c = 0; c < 4; ++c) b[c] = *(const float4*)(&Bs[tj + c][k]);
#pragma unroll
        for (int r = 0; r < 4; ++r)
#pragma unroll
            for (int c = 0; c < 4; ++c) {
                float d0 = a[r].x - b[c].x;
                float d1 = a[r].y - b[c].y;
                float d2 = a[r].z - b[c].z;
                float d3 = a[r].w - b[c].w;
                float s = acc[r][c];
                s = fmaf(d0, d0, s);
                s = fmaf(d1, d1, s);
                s = fmaf(d2, d2, s);
                s = fmaf(d3, d3, s);
                acc[r][c] = s;
            }
    }
#pragma unroll
    for (int r = 0; r < 4; ++r) {
        int i = bi + ti + r;
        float4 v;
        float* vp = &v.x;
        unsigned long long mk = ~0ULL;
#pragma unroll
        for (int c = 0; c < 4; ++c) {
            int j = bj + tj + c;
            vp[c] = (i == j) ? INF : sqrtf(fmaxf(acc[r][c], 1e-12f));
            unsigned long long key =
                ((unsigned long long)__float_as_uint(vp[c]) << 24) |
                ((unsigned long long)(unsigned)i << 12) | (unsigned)j;
            mk = key < mk ? key : mk;
        }
        *(float4*)(D + (size_t)i * N + (bj + tj)) = v;
        // 16-lane row-group reduce (lanes share t>>4; xor 1/2/4/8 stays in group)
#pragma unroll
        for (int m = 1; m < 16; m <<= 1) {
            unsigned long long o = __shfl_xor(mk, m, 64);
            mk = o < mk ? o : mk;
        }
        if ((t & 15) == 0) atomicMin(&best[i], mk);
    }
}

// ---------------------------------------------------------------------------
__global__ __launch_bounds__(256) void init_kernel(unsigned* comp,
                                                   unsigned long long* best,
                                                   unsigned* nedges, unsigned* done) {
    int i = blockIdx.x * 256 + threadIdx.x;
    if (i < N) {
        comp[i] = (unsigned)i;
        best[i] = ~0ULL;
    }
    if (i == 0) { *nedges = 0u; *done = 0u; }
}

// ---------------------------------------------------------------------------
// Cached-D minedge (R14-verified).
// ---------------------------------------------------------------------------
__global__ __launch_bounds__(256) void minedge_d_kernel(const float* __restrict__ D,
                                                        const unsigned* __restrict__ comp,
                                                        unsigned long long* __restrict__ best,
                                                        const unsigned* __restrict__ done) {
    if (*done) return;
    __shared__ unsigned compc[N];
    __shared__ unsigned long long keybuf[256];
    const int t = threadIdx.x;
    const int b = blockIdx.x;
    const int r = t >> 4;
    const int j = t & 15;
    const int rowv = b * 16 + r;

    for (int v = t; v < N; v += 256) compc[v] = comp[v];
    __syncthreads();
    const unsigned cr = compc[rowv];
    const float4* rowp = (const float4*)(D + (size_t)rowv * N);
    unsigned long long mykey = ~0ULL;
#pragma unroll 4
    for (int k = 0; k < 64; ++k) {
        float4 v4 = rowp[j + 16 * k];
        int c0 = 4 * (j + 16 * k);
        const float* vp = &v4.x;
#pragma unroll
        for (int q = 0; q < 4; ++q) {
            int c = c0 + q;
            if (compc[c] != cr) {
                unsigned long long key =
                    ((unsigned long long)__float_as_uint(vp[q]) << 24) |
                    ((unsigned long long)(unsigned)rowv << 12) | (unsigned)c;
                mykey = key < mykey ? key : mykey;
            }
        }
    }
    keybuf[t] = mykey;
    __syncthreads();
    if (t < 16) {
        unsigned long long k = ~0ULL;
#pragma unroll
        for (int i = 0; i < 16; ++i) {
            unsigned long long v2 = keybuf[t * 16 + i];
            k = v2 < k ? v2 : k;
        }
        if (k != ~0ULL) atomicMin(&best[compc[b * 16 + t]], k);
    }
}

// ---------------------------------------------------------------------------
// Recompute minedge (fallback path when ws too small; R13-verified).
// ---------------------------------------------------------------------------
__global__ __launch_bounds__(256) void minedge_kernel(const float* __restrict__ x,
                                                      const unsigned* __restrict__ comp,
                                                      unsigned long long* __restrict__ best,
                                                      const unsigned* __restrict__ done) {
    if (*done) return;
    __shared__ float xr[16][64];
    __shared__ float xc[64][68];
    __shared__ unsigned compr[16];
    __shared__ unsigned compc[64];
    __shared__ unsigned long long keybuf[256];
    const int t = threadIdx.x;
    const int b = blockIdx.x;
    const int r = t >> 4;
    const int rowv = b * 16 + r;

    {
        int row = t >> 4, f4 = t & 15;
        *(float4*)&xr[row][f4 * 4] =
            *(const float4*)(x + (size_t)(b * 16 + row) * DF + f4 * 4);
        if (t < 16) compr[t] = comp[b * 16 + t];
    }
    __syncthreads();
    const unsigned cr = compr[r];
    unsigned long long mykey = ~0ULL;

    for (int tile = 0; tile < 64; ++tile) {
        {
#pragma unroll
            for (int q = 0; q < 4; ++q) {
                int idx = t + 256 * q;
                int col = idx >> 4, k4 = (idx & 15) * 4;
                *(float4*)&xc[col][k4] =
                    *(const float4*)(x + (size_t)(tile * 64 + col) * DF + k4);
            }
            if (t < 64) compc[t] = comp[tile * 64 + t];
        }
        __syncthreads();
#pragma unroll
        for (int q = 0; q < 4; ++q) {
            int c = (t & 15) + 16 * q;
            unsigned cc = compc[c];
            if (cc != cr) {
                float s = 0.0f;
#pragma unroll
                for (int k = 0; k < 64; k += 4) {
                    float4 a = *(const float4*)&xr[r][k];
                    float4 bb = *(const float4*)&xc[c][k];
                    float d0 = a.x - bb.x;
                    float d1 = a.y - bb.y;
                    float d2 = a.z - bb.z;
                    float d3 = a.w - bb.w;
                    s = fmaf(d0, d0, s);
                    s = fmaf(d1, d1, s);
                    s = fmaf(d2, d2, s);
                    s = fmaf(d3, d3, s);
                }
                float w = sqrtf(fmaxf(s, 1e-12f));
                unsigned long long key =
                    ((unsigned long long)__float_as_uint(w) << 24) |
                    ((unsigned long long)(unsigned)rowv << 12) |
                    (unsigned)(tile * 64 + c);
                mykey = key < mykey ? key : mykey;
            }
        }
        __syncthreads();
    }
    keybuf[t] = mykey;
    __syncthreads();
    if (t < 16) {
        unsigned long long k = ~0ULL;
#pragma unroll
        for (int i = 0; i < 16; ++i) {
            unsigned long long v2 = keybuf[t * 16 + i];
            k = v2 < k ? v2 : k;
        }
        if (k != ~0ULL) atomicMin(&best[compr[t]], k);
    }
}

// ---------------------------------------------------------------------------
// Boruvka merge (R14-verified; thread-count agnostic, launched with 1024).
// ---------------------------------------------------------------------------
__global__ void merge_kernel(unsigned* comp, unsigned long long* best,
                             unsigned long long* edges, unsigned* nedges,
                             unsigned* done) {
    if (*done) return;
    __shared__ unsigned cl[N];
    __shared__ unsigned np[N];
    __shared__ unsigned cnt;
    const int t = threadIdx.x;
    const int bs = blockDim.x;
    for (int v = t; v < N; v += bs) cl[v] = comp[v];
    __syncthreads();
    for (int v = t; v < N; v += bs) {
        unsigned p;
        if (cl[v] == (unsigned)v) {
            unsigned long long k = best[v];
            p = (k != ~0ULL) ? cl[(unsigned)(k & 0xFFFu)] : (unsigned)v;
        } else {
            p = cl[v];
        }
        np[v] = p;
    }
    __syncthreads();
    for (int v = t; v < N; v += bs) {
        if (cl[v] == (unsigned)v) {
            unsigned p = np[v];
            if (p != (unsigned)v) {
                bool mutual = (np[p] == (unsigned)v);
                if (mutual && (unsigned)v < p) {
                    np[v] = (unsigned)v;
                } else {
                    unsigned idx = atomicAdd(nedges, 1u);
                    edges[idx] = best[v];
                }
            }
        }
    }
    __syncthreads();
    for (int it = 0; it < 12; ++it) {
        for (int v = t; v < N; v += bs) np[v] = np[np[v]];
        __syncthreads();
    }
    if (t == 0) cnt = 0;
    __syncthreads();
    unsigned local = 0;
    for (int v = t; v < N; v += bs) {
        comp[v] = np[v];
        best[v] = ~0ULL;
        if (np[v] == (unsigned)v) ++local;
    }
    atomicAdd(&cnt, local);
    __syncthreads();
    if (t == 0 && cnt == 1u) *done = 1u;
}

// ---------------------------------------------------------------------------
// Replay: CSR(+twin) -> Euler-tour list-ranking rooting -> ANSV -> S ->
// r-major sort -> segmented scan -> pointer-doubling -> scatter.
// ---------------------------------------------------------------------------
__global__ __launch_bounds__(1024) void replay_kernel(
        const unsigned long long* __restrict__ edges,
        const unsigned* __restrict__ nedges, float* __restrict__ out) {
    __shared__ __align__(16) unsigned char pool[156680];
    __shared__ unsigned chg;
    unsigned* off = (unsigned*)(pool + 65536);
    unsigned long long* ent = (unsigned long long*)(pool + 0);
    unsigned short* par = (unsigned short*)(pool + 81928);
    unsigned* keyw = (unsigned*)(pool + 90120);
    unsigned long long* key64 = (unsigned long long*)(pool + 0);
    unsigned long long* order = (unsigned long long*)(pool + 0);
    unsigned* ptr = (unsigned*)(pool + 106504);
    unsigned short* rankA = (unsigned short*)(pool + 106504);
    unsigned short* nxtA = (unsigned short*)(pool + 122888);
    unsigned short* twin = (unsigned short*)(pool + 139272);
    unsigned* Sa = (unsigned*)(pool + 32768);
    unsigned* Sb = (unsigned*)(pool + 49152);
    unsigned* T = (unsigned*)(pool + 65536);
    unsigned* vA = (unsigned*)(pool + 122888);
    unsigned* jA = (unsigned*)(pool + 139272);
    unsigned* vB = (unsigned*)(pool + 0);
    unsigned* jB = (unsigned*)(pool + 16384);
    unsigned* csum = (unsigned*)(pool + 155656);
    const int t = threadIdx.x;
    const unsigned ne = *nedges;
    const int ns = 2 * (int)ne;

    for (int v = t; v < N; v += 1024) off[v] = 0u;
    if (t == 0) off[N] = 0u;
    for (int k = t; k < N - 1; k += 1024) out[2 * k] = 0.0f;
    __syncthreads();
    for (int e = t; e < (int)ne; e += 1024) {
        unsigned long long k = edges[e];
        atomicAdd(&off[(unsigned)(k >> 12) & 0xFFFu], 1u);
        atomicAdd(&off[(unsigned)k & 0xFFFu], 1u);
    }
    __syncthreads();
    unsigned sloc = 0;
    unsigned loc[16];
    if (t < 256) {
        int base = t * 16;
#pragma unroll
        for (int i = 0; i < 16; ++i) {
            unsigned d = off[base + i];
            loc[i] = sloc;
            sloc += d;
        }
        csum[t] = sloc;
    }
    __syncthreads();
    for (int d = 1; d < 256; d <<= 1) {
        unsigned addv = 0;
        if (t < 256 && t >= d) addv = csum[t - d];
        __syncthreads();
        if (t < 256) csum[t] += addv;
        __syncthreads();
    }
    if (t < 256) {
        int base = t * 16;
        unsigned excl = csum[t] - sloc;
#pragma unroll
        for (int i = 0; i < 16; ++i) {
            unsigned o = loc[i] + excl;
            off[base + i] = o;
            keyw[base + i] = o;
        }
        if (t == 255) off[N] = csum[255];
    }
    __syncthreads();
    for (int e = t; e < (int)ne; e += 1024) {
        unsigned long long k = edges[e];
        unsigned a = (unsigned)(k >> 12) & 0xFFFu;
        unsigned b = (unsigned)k & 0xFFFu;
        unsigned long long wb = k >> 24;
        unsigned p1 = atomicAdd(&keyw[a], 1u);
        unsigned p2 = atomicAdd(&keyw[b], 1u);
        ent[p1] = (wb << 12) | b;
        ent[p2] = (wb << 12) | a;
        twin[p1] = (unsigned short)p2;
        twin[p2] = (unsigned short)p1;
    }
    __syncthreads();
    const unsigned s0 = off[0];
    for (int s = t; s < ns; s += 1024) {
        unsigned v = (unsigned)ent[s] & 0xFFFu;
        unsigned t2 = twin[s];
        unsigned nx = t2 + 1u;
        if (nx == off[v + 1]) nx = off[v];
        if (nx == s0) nx = 0xFFFFu;
        nxtA[s] = (unsigned short)nx;
        rankA[s] = 1;
    }
    __syncthreads();
    for (int round = 0; round < 13; ++round) {
        unsigned short rr[8], nn[8];
#pragma unroll
        for (int q = 0; q < 8; ++q) {
            int s = t + 1024 * q;
            rr[q] = 0;
            nn[q] = 0xFFFFu;
            if (s < ns) {
                unsigned n2 = nxtA[s];
                if (n2 != 0xFFFFu) {
                    rr[q] = rankA[n2];
                    nn[q] = nxtA[n2];
                }
            }
        }
        __syncthreads();
#pragma unroll
        for (int q = 0; q < 8; ++q) {
            int s = t + 1024 * q;
            if (s < ns && nxtA[s] != 0xFFFFu) {
                rankA[s] = (unsigned short)(rankA[s] + rr[q]);
                nxtA[s] = nn[q];
            }
        }
        __syncthreads();
    }
    for (int s = t; s < ns; s += 1024) {
        unsigned t2 = twin[s];
        if (rankA[s] > rankA[t2]) {
            unsigned v = (unsigned)ent[s] & 0xFFFu;
            par[v] = (unsigned short)((unsigned)ent[t2] & 0xFFFu);
            keyw[v] = (unsigned)(ent[s] >> 12);
        }
    }
    if (t == 0) {
        par[0] = 0;
        chg = 0u;
    }
    __syncthreads();
    for (int v = t; v < N; v += 1024) {
        key64[v] = (v == 0) ? ~0ULL
                            : (((unsigned long long)keyw[v]) << 24) |
                                  ((unsigned long long)par[v] << 12) | (unsigned)v;
    }
    __syncthreads();
    for (int v = t; v < N; v += 1024) ptr[v] = (v == 0) ? 0u : (unsigned)par[v];
    __syncthreads();
    for (;;) {
        for (int v = t; v < N; v += 1024) {
            unsigned p = ptr[v];
            if (key64[p] <= key64[v]) {
                unsigned q = ptr[p];
                if (q != p) {
                    ptr[v] = q;
                    chg = 1u;
                }
            }
        }
        __syncthreads();
        unsigned fin = (chg == 0u);
        __syncthreads();
        if (t == 0) chg = 0u;
        __syncthreads();
        if (fin) break;
    }
    unsigned* Sc = Sa;
    unsigned* Sn = Sb;
    for (int v = t; v < N; v += 1024) Sc[v] = 1u;
    __syncthreads();
    for (int round = 0; round < 64; ++round) {
        for (int v = t; v < N; v += 1024) Sn[v] = 1u;
        __syncthreads();
        for (int v = t; v < N; v += 1024)
            if (v != 0) atomicAdd(&Sn[ptr[v]], Sc[v]);
        __syncthreads();
        for (int v = t; v < N; v += 1024)
            if (Sn[v] != Sc[v]) chg = 1u;
        __syncthreads();
        unsigned fin = (chg == 0u);
        __syncthreads();
        if (t == 0) chg = 0u;
        __syncthreads();
        unsigned* tmp = Sc; Sc = Sn; Sn = tmp;
        if (fin) break;
    }
    for (int v = t; v < N; v += 1024) {
        order[v] = (v == 0)
                       ? (0xFFFFFull << 44)
                       : (((unsigned long long)ptr[v]) << 44) |
                             (((unsigned long long)keyw[v]) << 12) | (unsigned)v;
    }
    __syncthreads();
    for (unsigned k = 2; k <= 4096; k <<= 1) {
        for (unsigned j = k >> 1; j > 0; j >>= 1) {
            for (unsigned i = t; i < 4096; i += 1024) {
                unsigned p = i ^ j;
                if (p > i) {
                    unsigned long long a = order[i], b = order[p];
                    bool up = ((i & k) == 0);
                    if ((a > b) == up) {
                        order[i] = b;
                        order[p] = a;
                    }
                }
            }
            __syncthreads();
        }
    }
    for (int i = t; i < 4096; i += 1024) {
        unsigned vv = (unsigned)order[i] & 0xFFFu;
        T[i] = Sc[vv];
    }
    __syncthreads();
    for (int d = 1; d < 4096; d <<= 1) {
        unsigned addv[4];
#pragma unroll
        for (int q = 0; q < 4; ++q) {
            int i = t + 1024 * q;
            addv[q] = 0;
            if (i >= d && (order[i] >> 44) == (order[i - d] >> 44)) addv[q] = T[i - d];
        }
        __syncthreads();
#pragma unroll
        for (int q = 0; q < 4; ++q) T[t + 1024 * q] += addv[q];
        __syncthreads();
    }
    for (int i = t; i < 4096; i += 1024) {
        unsigned vv = (unsigned)order[i] & 0xFFFu;
        if (vv) {
            vA[vv] = 1u + T[i] - Sc[vv];
            jA[vv] = ptr[vv];
        }
    }
    if (t == 0) {
        vA[0] = 0u;
        jA[0] = 0u;
    }
    __syncthreads();
    {
        unsigned *va = vA, *vb = vB, *ja = jA, *jb = jB;
        for (int r = 0; r < 12; ++r) {
            for (int v = t; v < N; v += 1024) {
                unsigned j2 = ja[v];
                vb[v] = va[v] + va[j2];
                jb[v] = ja[j2];
            }
            __syncthreads();
            unsigned* tmp;
            tmp = va; va = vb; vb = tmp;
            tmp = ja; ja = jb; jb = tmp;
        }
        for (int v = t; v < N; v += 1024) {
            if (v) out[2 * (va[v] - 1) + 1] = __uint_as_float(keyw[v]);
        }
    }
}

// ---------------------------------------------------------------------------
extern "C" void kernel_launch(void* const* d_in, const int* in_sizes, int n_in,
                              void* d_out, int out_size, void* d_ws, size_t ws_size,
                              hipStream_t stream) {
    const float* x = (const float*)d_in[0];
    float* out = (float*)d_out;  // [N-1][2]: (birth=0, death)
    const size_t dbytes = (size_t)N * N * 4;

    if (ws_size >= dbytes + 81920) {
        // Cached-D path (R14 structure + round-0 fused into build_d).
        float* D = (float*)d_ws;
        unsigned char* st = (unsigned char*)d_ws + dbytes;
        unsigned long long* best = (unsigned long long*)st;            // 32 KB
        unsigned* comp = (unsigned*)(st + 32768);                      // 16 KB
        unsigned long long* edges = (unsigned long long*)(st + 49152); // 32760 B
        unsigned* nedges = (unsigned*)(st + 81912);
        unsigned* done = (unsigned*)(st + 81916);

        dim3 grid(N / 64, N / 64);
        init_kernel<<<16, 256, 0, stream>>>(comp, best, nedges, done);
        build_d_kernel<<<grid, 256, 0, stream>>>(x, D, best);  // emits round-0 best
        merge_kernel<<<1, 1024, 0, stream>>>(comp, best, edges, nedges, done);
        for (int r = 1; r < 12; ++r) {
            minedge_d_kernel<<<256, 256, 0, stream>>>(D, comp, best, done);
            merge_kernel<<<1, 1024, 0, stream>>>(comp, best, edges, nedges, done);
        }
        replay_kernel<<<1, 1024, 0, stream>>>(edges, nedges, out);
    } else {
        // Recompute fallback (R13-verified structure).
        unsigned char* ws = (unsigned char*)d_ws;
        unsigned* comp = (unsigned*)ws;                                  // 16 KB
        unsigned long long* best = (unsigned long long*)(ws + 16384);    // 32 KB
        unsigned long long* edges = (unsigned long long*)(ws + 49152);   // 32 KB
        unsigned* nedges = (unsigned*)(ws + 81920);
        unsigned* done = (unsigned*)(ws + 81984);

        init_kernel<<<16, 256, 0, stream>>>(comp, best, nedges, done);
        for (int r = 0; r < 12; ++r) {
            minedge_kernel<<<256, 256, 0, stream>>>(x, comp, best, done);
            merge_kernel<<<1, 1024, 0, stream>>>(comp, best, edges, nedges, done);
        }
        replay_kernel<<<1, 1024, 0, stream>>>(edges, nedges, out);
    }
}

// Round 19
// 472.637 us; speedup vs baseline: 1.2211x; 1.0291x over previous
//
#include <hip/hip_runtime.h>
#include <math.h>

// RipsLayer: dim-0 persistence of Rips filtration on 4096 points in R^64.
// R19 = R16/R18 structure (verified 486-491us) + two cuts:
//  (1) SYMMETRIC build_d: D bitwise-symmetric under our fmaf sequence
//      ((-d)^2 == d^2 exactly), so compute only 2080 upper-triangle tiles
//      and write off-diagonal tiles twice (direct + LDS-transposed).
//      Round-0 best gets row-side keys (w,i,j) AND col-side keys (w,j,i)
//      (colbuf reduce + atomicMin). Compute phase halves.
//  (2) replay bitonic sort: j=2,1 tail phases of each k-level fused into
//      one register-local phase (thread owns [4t,4t+4); i&k constant for
//      k>=4) — same comparison network, 78 -> 67 barriers.
// All else verbatim from R18 (verified): split Boruvka small kernels
// (fusion loses on this chip: R15 +55%, R17 +18%), cached-D minedge,
// Euler-tour rooting -> ANSV -> S -> r-major sort -> segscan -> doubling.

#define N 4096
#define DF 64
#define INF __builtin_huge_valf()

// ---------------------------------------------------------------------------
// Symmetric build_d + round-0 best. Grid = 2080 upper-triangle tiles.
// ---------------------------------------------------------------------------
__global__ __launch_bounds__(256) void build_d_kernel(const float* __restrict__ x,
                                                      float* __restrict__ D,
                                                      unsigned long long* __restrict__ best) {
    __shared__ float As[64][68];
    __shared__ float Bs[64][68];
    __shared__ float Ts[64][68];                 // transposed-tile staging
    __shared__ unsigned long long colbuf[64][16];  // col-side key reduce
    const int t = threadIdx.x;

    // decode upper-triangle tile (br <= bc)
    int br = 0;
    {
        int rem = blockIdx.x;
        while (rem >= 64 - br) {
            rem -= 64 - br;
            ++br;
        }
        br = br;  // row
        // column:
        int bc = br + rem;
        // stash in shared-less registers via recompute below
        // (use locals)
        // fallthrough handled by variables below
        // (we keep bc in a register)
        // -- implemented inline:
        const int bi = br * 64;
        const int bj = bc * 64;

#pragma unroll
        for (int g = 0; g < 4; ++g) {
            int idx = t + 256 * g;
            int row = idx >> 4;
            int k4 = (idx & 15) << 2;
            *(float4*)(&As[row][k4]) =
                *(const float4*)(x + (size_t)(bi + row) * DF + k4);
            *(float4*)(&Bs[row][k4]) =
                *(const float4*)(x + (size_t)(bj + row) * DF + k4);
        }
        __syncthreads();

        const int ti = (t >> 4) << 2;
        const int tj = (t & 15) << 2;
        float acc[4][4];
#pragma unroll
        for (int r = 0; r < 4; ++r)
#pragma unroll
            for (int c = 0; c < 4; ++c) acc[r][c] = 0.0f;

        for (int k = 0; k < 64; k += 4) {
            float4 a[4], b[4];
#pragma unroll
            for (int r = 0; r < 4; ++r) a[r] = *(const float4*)(&As[ti + r][k]);
#pragma unroll
            for (int c = 0; c < 4; ++c) b[c] = *(const float4*)(&Bs[tj + c][k]);
#pragma unroll
            for (int r = 0; r < 4; ++r)
#pragma unroll
                for (int c = 0; c < 4; ++c) {
                    float d0 = a[r].x - b[c].x;
                    float d1 = a[r].y - b[c].y;
                    float d2 = a[r].z - b[c].z;
                    float d3 = a[r].w - b[c].w;
                    float s = acc[r][c];
                    s = fmaf(d0, d0, s);
                    s = fmaf(d1, d1, s);
                    s = fmaf(d2, d2, s);
                    s = fmaf(d3, d3, s);
                    acc[r][c] = s;
                }
        }

        // values + direct tile write + row-side round-0 keys
        float val[4][4];
#pragma unroll
        for (int r = 0; r < 4; ++r) {
            int i = bi + ti + r;
            float4 v;
            float* vp = &v.x;
            unsigned long long mk = ~0ULL;
#pragma unroll
            for (int c = 0; c < 4; ++c) {
                int j = bj + tj + c;
                float w = (i == j) ? INF : sqrtf(fmaxf(acc[r][c], 1e-12f));
                val[r][c] = w;
                vp[c] = w;
                unsigned long long key =
                    ((unsigned long long)__float_as_uint(w) << 24) |
                    ((unsigned long long)(unsigned)i << 12) | (unsigned)j;
                mk = key < mk ? key : mk;
            }
            *(float4*)(D + (size_t)i * N + (bj + tj)) = v;
#pragma unroll
            for (int m = 1; m < 16; m <<= 1) {
                unsigned long long o = __shfl_xor(mk, m, 64);
                mk = o < mk ? o : mk;
            }
            if ((t & 15) == 0) atomicMin(&best[i], mk);
        }

        // off-diagonal: transposed tile write + col-side round-0 keys
        if (br != bc) {
#pragma unroll
            for (int c = 0; c < 4; ++c) {
                unsigned long long ck = ~0ULL;
                int j = bj + tj + c;
#pragma unroll
                for (int r = 0; r < 4; ++r) {
                    int i = bi + ti + r;
                    float w = val[r][c];
                    Ts[tj + c][ti + r] = w;
                    unsigned long long key =
                        ((unsigned long long)__float_as_uint(w) << 24) |
                        ((unsigned long long)(unsigned)j << 12) | (unsigned)i;
                    ck = key < ck ? key : ck;
                }
                colbuf[tj + c][t >> 4] = ck;
            }
            __syncthreads();
            {
                int row = t >> 2;
                int seg = (t & 3) * 16;
                float4* dst = (float4*)(D + (size_t)(bj + row) * N + bi + seg);
#pragma unroll
                for (int q = 0; q < 4; ++q)
                    dst[q] = *(const float4*)(&Ts[row][seg + 4 * q]);
            }
            if (t < 64) {
                unsigned long long k = ~0ULL;
#pragma unroll
                for (int i2 = 0; i2 < 16; ++i2) {
                    unsigned long long v2 = colbuf[t][i2];
                    k = v2 < k ? v2 : k;
                }
                atomicMin(&best[bj + t], k);
            }
        }
    }
}

// ---------------------------------------------------------------------------
__global__ __launch_bounds__(256) void init_kernel(unsigned* comp,
                                                   unsigned long long* best,
                                                   unsigned* nedges, unsigned* done) {
    int i = blockIdx.x * 256 + threadIdx.x;
    if (i < N) {
        comp[i] = (unsigned)i;
        best[i] = ~0ULL;
    }
    if (i == 0) { *nedges = 0u; *done = 0u; }
}

// ---------------------------------------------------------------------------
// Cached-D minedge (R14-verified).
// ---------------------------------------------------------------------------
__global__ __launch_bounds__(256) void minedge_d_kernel(const float* __restrict__ D,
                                                        const unsigned* __restrict__ comp,
                                                        unsigned long long* __restrict__ best,
                                                        const unsigned* __restrict__ done) {
    if (*done) return;
    __shared__ unsigned compc[N];
    __shared__ unsigned long long keybuf[256];
    const int t = threadIdx.x;
    const int b = blockIdx.x;
    const int r = t >> 4;
    const int j = t & 15;
    const int rowv = b * 16 + r;

    for (int v = t; v < N; v += 256) compc[v] = comp[v];
    __syncthreads();
    const unsigned cr = compc[rowv];
    const float4* rowp = (const float4*)(D + (size_t)rowv * N);
    unsigned long long mykey = ~0ULL;
#pragma unroll 4
    for (int k = 0; k < 64; ++k) {
        float4 v4 = rowp[j + 16 * k];
        int c0 = 4 * (j + 16 * k);
        const float* vp = &v4.x;
#pragma unroll
        for (int q = 0; q < 4; ++q) {
            int c = c0 + q;
            if (compc[c] != cr) {
                unsigned long long key =
                    ((unsigned long long)__float_as_uint(vp[q]) << 24) |
                    ((unsigned long long)(unsigned)rowv << 12) | (unsigned)c;
                mykey = key < mykey ? key : mykey;
            }
        }
    }
    keybuf[t] = mykey;
    __syncthreads();
    if (t < 16) {
        unsigned long long k = ~0ULL;
#pragma unroll
        for (int i = 0; i < 16; ++i) {
            unsigned long long v2 = keybuf[t * 16 + i];
            k = v2 < k ? v2 : k;
        }
        if (k != ~0ULL) atomicMin(&best[compc[b * 16 + t]], k);
    }
}

// ---------------------------------------------------------------------------
// Recompute minedge (fallback path when ws too small; R13-verified).
// ---------------------------------------------------------------------------
__global__ __launch_bounds__(256) void minedge_kernel(const float* __restrict__ x,
                                                      const unsigned* __restrict__ comp,
                                                      unsigned long long* __restrict__ best,
                                                      const unsigned* __restrict__ done) {
    if (*done) return;
    __shared__ float xr[16][64];
    __shared__ float xc[64][68];
    __shared__ unsigned compr[16];
    __shared__ unsigned compc[64];
    __shared__ unsigned long long keybuf[256];
    const int t = threadIdx.x;
    const int b = blockIdx.x;
    const int r = t >> 4;
    const int rowv = b * 16 + r;

    {
        int row = t >> 4, f4 = t & 15;
        *(float4*)&xr[row][f4 * 4] =
            *(const float4*)(x + (size_t)(b * 16 + row) * DF + f4 * 4);
        if (t < 16) compr[t] = comp[b * 16 + t];
    }
    __syncthreads();
    const unsigned cr = compr[r];
    unsigned long long mykey = ~0ULL;

    for (int tile = 0; tile < 64; ++tile) {
        {
#pragma unroll
            for (int q = 0; q < 4; ++q) {
                int idx = t + 256 * q;
                int col = idx >> 4, k4 = (idx & 15) * 4;
                *(float4*)&xc[col][k4] =
                    *(const float4*)(x + (size_t)(tile * 64 + col) * DF + k4);
            }
            if (t < 64) compc[t] = comp[tile * 64 + t];
        }
        __syncthreads();
#pragma unroll
        for (int q = 0; q < 4; ++q) {
            int c = (t & 15) + 16 * q;
            unsigned cc = compc[c];
            if (cc != cr) {
                float s = 0.0f;
#pragma unroll
                for (int k = 0; k < 64; k += 4) {
                    float4 a = *(const float4*)&xr[r][k];
                    float4 bb = *(const float4*)&xc[c][k];
                    float d0 = a.x - bb.x;
                    float d1 = a.y - bb.y;
                    float d2 = a.z - bb.z;
                    float d3 = a.w - bb.w;
                    s = fmaf(d0, d0, s);
                    s = fmaf(d1, d1, s);
                    s = fmaf(d2, d2, s);
                    s = fmaf(d3, d3, s);
                }
                float w = sqrtf(fmaxf(s, 1e-12f));
                unsigned long long key =
                    ((unsigned long long)__float_as_uint(w) << 24) |
                    ((unsigned long long)(unsigned)rowv << 12) |
                    (unsigned)(tile * 64 + c);
                mykey = key < mykey ? key : mykey;
            }
        }
        __syncthreads();
    }
    keybuf[t] = mykey;
    __syncthreads();
    if (t < 16) {
        unsigned long long k = ~0ULL;
#pragma unroll
        for (int i = 0; i < 16; ++i) {
            unsigned long long v2 = keybuf[t * 16 + i];
            k = v2 < k ? v2 : k;
        }
        if (k != ~0ULL) atomicMin(&best[compr[t]], k);
    }
}

// ---------------------------------------------------------------------------
// Boruvka merge (R14-verified; thread-count agnostic, launched with 1024).
// ---------------------------------------------------------------------------
__global__ void merge_kernel(unsigned* comp, unsigned long long* best,
                             unsigned long long* edges, unsigned* nedges,
                             unsigned* done) {
    if (*done) return;
    __shared__ unsigned cl[N];
    __shared__ unsigned np[N];
    __shared__ unsigned cnt;
    const int t = threadIdx.x;
    const int bs = blockDim.x;
    for (int v = t; v < N; v += bs) cl[v] = comp[v];
    __syncthreads();
    for (int v = t; v < N; v += bs) {
        unsigned p;
        if (cl[v] == (unsigned)v) {
            unsigned long long k = best[v];
            p = (k != ~0ULL) ? cl[(unsigned)(k & 0xFFFu)] : (unsigned)v;
        } else {
            p = cl[v];
        }
        np[v] = p;
    }
    __syncthreads();
    for (int v = t; v < N; v += bs) {
        if (cl[v] == (unsigned)v) {
            unsigned p = np[v];
            if (p != (unsigned)v) {
                bool mutual = (np[p] == (unsigned)v);
                if (mutual && (unsigned)v < p) {
                    np[v] = (unsigned)v;
                } else {
                    unsigned idx = atomicAdd(nedges, 1u);
                    edges[idx] = best[v];
                }
            }
        }
    }
    __syncthreads();
    for (int it = 0; it < 12; ++it) {
        for (int v = t; v < N; v += bs) np[v] = np[np[v]];
        __syncthreads();
    }
    if (t == 0) cnt = 0;
    __syncthreads();
    unsigned local = 0;
    for (int v = t; v < N; v += bs) {
        comp[v] = np[v];
        best[v] = ~0ULL;
        if (np[v] == (unsigned)v) ++local;
    }
    atomicAdd(&cnt, local);
    __syncthreads();
    if (t == 0 && cnt == 1u) *done = 1u;
}

// ---------------------------------------------------------------------------
// Replay: CSR(+twin) -> Euler-tour list-ranking rooting -> ANSV -> S ->
// r-major sort -> segmented scan -> pointer-doubling -> scatter.
// ---------------------------------------------------------------------------
__global__ __launch_bounds__(1024) void replay_kernel(
        const unsigned long long* __restrict__ edges,
        const unsigned* __restrict__ nedges, float* __restrict__ out) {
    __shared__ __align__(16) unsigned char pool[156680];
    __shared__ unsigned chg;
    unsigned* off = (unsigned*)(pool + 65536);
    unsigned long long* ent = (unsigned long long*)(pool + 0);
    unsigned short* par = (unsigned short*)(pool + 81928);
    unsigned* keyw = (unsigned*)(pool + 90120);
    unsigned long long* key64 = (unsigned long long*)(pool + 0);
    unsigned long long* order = (unsigned long long*)(pool + 0);
    unsigned* ptr = (unsigned*)(pool + 106504);
    unsigned short* rankA = (unsigned short*)(pool + 106504);
    unsigned short* nxtA = (unsigned short*)(pool + 122888);
    unsigned short* twin = (unsigned short*)(pool + 139272);
    unsigned* Sa = (unsigned*)(pool + 32768);
    unsigned* Sb = (unsigned*)(pool + 49152);
    unsigned* T = (unsigned*)(pool + 65536);
    unsigned* vA = (unsigned*)(pool + 122888);
    unsigned* jA = (unsigned*)(pool + 139272);
    unsigned* vB = (unsigned*)(pool + 0);
    unsigned* jB = (unsigned*)(pool + 16384);
    unsigned* csum = (unsigned*)(pool + 155656);
    const int t = threadIdx.x;
    const unsigned ne = *nedges;
    const int ns = 2 * (int)ne;

    for (int v = t; v < N; v += 1024) off[v] = 0u;
    if (t == 0) off[N] = 0u;
    for (int k = t; k < N - 1; k += 1024) out[2 * k] = 0.0f;
    __syncthreads();
    for (int e = t; e < (int)ne; e += 1024) {
        unsigned long long k = edges[e];
        atomicAdd(&off[(unsigned)(k >> 12) & 0xFFFu], 1u);
        atomicAdd(&off[(unsigned)k & 0xFFFu], 1u);
    }
    __syncthreads();
    unsigned sloc = 0;
    unsigned loc[16];
    if (t < 256) {
        int base = t * 16;
#pragma unroll
        for (int i = 0; i < 16; ++i) {
            unsigned d = off[base + i];
            loc[i] = sloc;
            sloc += d;
        }
        csum[t] = sloc;
    }
    __syncthreads();
    for (int d = 1; d < 256; d <<= 1) {
        unsigned addv = 0;
        if (t < 256 && t >= d) addv = csum[t - d];
        __syncthreads();
        if (t < 256) csum[t] += addv;
        __syncthreads();
    }
    if (t < 256) {
        int base = t * 16;
        unsigned excl = csum[t] - sloc;
#pragma unroll
        for (int i = 0; i < 16; ++i) {
            unsigned o = loc[i] + excl;
            off[base + i] = o;
            keyw[base + i] = o;
        }
        if (t == 255) off[N] = csum[255];
    }
    __syncthreads();
    for (int e = t; e < (int)ne; e += 1024) {
        unsigned long long k = edges[e];
        unsigned a = (unsigned)(k >> 12) & 0xFFFu;
        unsigned b = (unsigned)k & 0xFFFu;
        unsigned long long wb = k >> 24;
        unsigned p1 = atomicAdd(&keyw[a], 1u);
        unsigned p2 = atomicAdd(&keyw[b], 1u);
        ent[p1] = (wb << 12) | b;
        ent[p2] = (wb << 12) | a;
        twin[p1] = (unsigned short)p2;
        twin[p2] = (unsigned short)p1;
    }
    __syncthreads();
    const unsigned s0 = off[0];
    for (int s = t; s < ns; s += 1024) {
        unsigned v = (unsigned)ent[s] & 0xFFFu;
        unsigned t2 = twin[s];
        unsigned nx = t2 + 1u;
        if (nx == off[v + 1]) nx = off[v];
        if (nx == s0) nx = 0xFFFFu;
        nxtA[s] = (unsigned short)nx;
        rankA[s] = 1;
    }
    __syncthreads();
    for (int round = 0; round < 13; ++round) {
        unsigned short rr[8], nn[8];
#pragma unroll
        for (int q = 0; q < 8; ++q) {
            int s = t + 1024 * q;
            rr[q] = 0;
            nn[q] = 0xFFFFu;
            if (s < ns) {
                unsigned n2 = nxtA[s];
                if (n2 != 0xFFFFu) {
                    rr[q] = rankA[n2];
                    nn[q] = nxtA[n2];
                }
            }
        }
        __syncthreads();
#pragma unroll
        for (int q = 0; q < 8; ++q) {
            int s = t + 1024 * q;
            if (s < ns && nxtA[s] != 0xFFFFu) {
                rankA[s] = (unsigned short)(rankA[s] + rr[q]);
                nxtA[s] = nn[q];
            }
        }
        __syncthreads();
    }
    for (int s = t; s < ns; s += 1024) {
        unsigned t2 = twin[s];
        if (rankA[s] > rankA[t2]) {
            unsigned v = (unsigned)ent[s] & 0xFFFu;
            par[v] = (unsigned short)((unsigned)ent[t2] & 0xFFFu);
            keyw[v] = (unsigned)(ent[s] >> 12);
        }
    }
    if (t == 0) {
        par[0] = 0;
        chg = 0u;
    }
    __syncthreads();
    for (int v = t; v < N; v += 1024) {
        key64[v] = (v == 0) ? ~0ULL
                            : (((unsigned long long)keyw[v]) << 24) |
                                  ((unsigned long long)par[v] << 12) | (unsigned)v;
    }
    __syncthreads();
    for (int v = t; v < N; v += 1024) ptr[v] = (v == 0) ? 0u : (unsigned)par[v];
    __syncthreads();
    for (;;) {
        for (int v = t; v < N; v += 1024) {
            unsigned p = ptr[v];
            if (key64[p] <= key64[v]) {
                unsigned q = ptr[p];
                if (q != p) {
                    ptr[v] = q;
                    chg = 1u;
                }
            }
        }
        __syncthreads();
        unsigned fin = (chg == 0u);
        __syncthreads();
        if (t == 0) chg = 0u;
        __syncthreads();
        if (fin) break;
    }
    unsigned* Sc = Sa;
    unsigned* Sn = Sb;
    for (int v = t; v < N; v += 1024) Sc[v] = 1u;
    __syncthreads();
    for (int round = 0; round < 64; ++round) {
        for (int v = t; v < N; v += 1024) Sn[v] = 1u;
        __syncthreads();
        for (int v = t; v < N; v += 1024)
            if (v != 0) atomicAdd(&Sn[ptr[v]], Sc[v]);
        __syncthreads();
        for (int v = t; v < N; v += 1024)
            if (Sn[v] != Sc[v]) chg = 1u;
        __syncthreads();
        unsigned fin = (chg == 0u);
        __syncthreads();
        if (t == 0) chg = 0u;
        __syncthreads();
        unsigned* tmp = Sc; Sc = Sn; Sn = tmp;
        if (fin) break;
    }
    for (int v = t; v < N; v += 1024) {
        order[v] = (v == 0)
                       ? (0xFFFFFull << 44)
                       : (((unsigned long long)ptr[v]) << 44) |
                             (((unsigned long long)keyw[v]) << 12) | (unsigned)v;
    }
    __syncthreads();
    // bitonic sort; j=2,1 tail of each level fused into one local phase
    for (unsigned k = 2; k <= 4096; k <<= 1) {
        for (unsigned j = k >> 1; j >= 4; j >>= 1) {
            for (unsigned i = t; i < 4096; i += 1024) {
                unsigned p = i ^ j;
                if (p > i) {
                    unsigned long long a = order[i], b = order[p];
                    bool up = ((i & k) == 0);
                    if ((a > b) == up) {
                        order[i] = b;
                        order[p] = a;
                    }
                }
            }
            __syncthreads();
        }
        {
            int base = 4 * t;
            unsigned long long e0 = order[base + 0];
            unsigned long long e1 = order[base + 1];
            unsigned long long e2 = order[base + 2];
            unsigned long long e3 = order[base + 3];
            if (k >= 4) {
                bool up = (((unsigned)base & k) == 0);
                unsigned long long tmp;
                if ((e0 > e2) == up) { tmp = e0; e0 = e2; e2 = tmp; }
                if ((e1 > e3) == up) { tmp = e1; e1 = e3; e3 = tmp; }
                if ((e0 > e1) == up) { tmp = e0; e0 = e1; e1 = tmp; }
                if ((e2 > e3) == up) { tmp = e2; e2 = e3; e3 = tmp; }
            } else {  // k == 2: pair dirs (up, down)
                unsigned long long tmp;
                if (e0 > e1) { tmp = e0; e0 = e1; e1 = tmp; }
                if (e2 < e3) { tmp = e2; e2 = e3; e3 = tmp; }
            }
            order[base + 0] = e0;
            order[base + 1] = e1;
            order[base + 2] = e2;
            order[base + 3] = e3;
            __syncthreads();
        }
    }
    for (int i = t; i < 4096; i += 1024) {
        unsigned vv = (unsigned)order[i] & 0xFFFu;
        T[i] = Sc[vv];
    }
    __syncthreads();
    for (int d = 1; d < 4096; d <<= 1) {
        unsigned addv[4];
#pragma unroll
        for (int q = 0; q < 4; ++q) {
            int i = t + 1024 * q;
            addv[q] = 0;
            if (i >= d && (order[i] >> 44) == (order[i - d] >> 44)) addv[q] = T[i - d];
        }
        __syncthreads();
#pragma unroll
        for (int q = 0; q < 4; ++q) T[t + 1024 * q] += addv[q];
        __syncthreads();
    }
    for (int i = t; i < 4096; i += 1024) {
        unsigned vv = (unsigned)order[i] & 0xFFFu;
        if (vv) {
            vA[vv] = 1u + T[i] - Sc[vv];
            jA[vv] = ptr[vv];
        }
    }
    if (t == 0) {
        vA[0] = 0u;
        jA[0] = 0u;
    }
    __syncthreads();
    {
        unsigned *va = vA, *vb = vB, *ja = jA, *jb = jB;
        for (int r = 0; r < 12; ++r) {
            for (int v = t; v < N; v += 1024) {
                unsigned j2 = ja[v];
                vb[v] = va[v] + va[j2];
                jb[v] = ja[j2];
            }
            __syncthreads();
            unsigned* tmp;
            tmp = va; va = vb; vb = tmp;
            tmp = ja; ja = jb; jb = tmp;
        }
        for (int v = t; v < N; v += 1024) {
            if (v) out[2 * (va[v] - 1) + 1] = __uint_as_float(keyw[v]);
        }
    }
}

// ---------------------------------------------------------------------------
extern "C" void kernel_launch(void* const* d_in, const int* in_sizes, int n_in,
                              void* d_out, int out_size, void* d_ws, size_t ws_size,
                              hipStream_t stream) {
    const float* x = (const float*)d_in[0];
    float* out = (float*)d_out;  // [N-1][2]: (birth=0, death)
    const size_t dbytes = (size_t)N * N * 4;

    if (ws_size >= dbytes + 81920) {
        float* D = (float*)d_ws;
        unsigned char* st = (unsigned char*)d_ws + dbytes;
        unsigned long long* best = (unsigned long long*)st;            // 32 KB
        unsigned* comp = (unsigned*)(st + 32768);                      // 16 KB
        unsigned long long* edges = (unsigned long long*)(st + 49152); // 32760 B
        unsigned* nedges = (unsigned*)(st + 81912);
        unsigned* done = (unsigned*)(st + 81916);

        init_kernel<<<16, 256, 0, stream>>>(comp, best, nedges, done);
        build_d_kernel<<<2080, 256, 0, stream>>>(x, D, best);  // upper-tri tiles
        merge_kernel<<<1, 1024, 0, stream>>>(comp, best, edges, nedges, done);
        for (int r = 1; r < 12; ++r) {
            minedge_d_kernel<<<256, 256, 0, stream>>>(D, comp, best, done);
            merge_kernel<<<1, 1024, 0, stream>>>(comp, best, edges, nedges, done);
        }
        replay_kernel<<<1, 1024, 0, stream>>>(edges, nedges, out);
    } else {
        // Recompute fallback (R13-verified structure).
        unsigned char* ws = (unsigned char*)d_ws;
        unsigned* comp = (unsigned*)ws;                                  // 16 KB
        unsigned long long* best = (unsigned long long*)(ws + 16384);    // 32 KB
        unsigned long long* edges = (unsigned long long*)(ws + 49152);   // 32 KB
        unsigned* nedges = (unsigned*)(ws + 81920);
        unsigned* done = (unsigned*)(ws + 81984);

        init_kernel<<<16, 256, 0, stream>>>(comp, best, nedges, done);
        for (int r = 0; r < 12; ++r) {
            minedge_kernel<<<256, 256, 0, stream>>>(x, comp, best, done);
            merge_kernel<<<1, 1024, 0, stream>>>(comp, best, edges, nedges, done);
        }
        replay_kernel<<<1, 1024, 0, stream>>>(edges, nedges, out);
    }
}

// Round 20
// 463.541 us; speedup vs baseline: 1.2450x; 1.0196x over previous
//
#include <hip/hip_runtime.h>
#include <math.h>

// RipsLayer: dim-0 persistence of Rips filtration on 4096 points in R^64.
// R20 = R19 (verified 473us) + merge launches eliminated by REDUNDANT
// LOCAL MERGE (no sync primitives — the failure mode of R15 grid.sync and
// R17 ticket/fence): every minedge block recomputes the deterministic
// merge from best+comp_prev in its own LDS; only block 0 writes comp_new
// and emits edges. Hazards handled structurally:
//   - comp double-buffered (block0's comp_new write cannot race slower
//     blocks' comp_prev reads),
//   - best 3-buffer rotation (reset target consumed 2 kernel boundaries
//     ago),
//   - all cross-round visibility via kernel launch boundaries (the
//     mechanism the split pipeline already used).
// Local merge: hook + chg-early-exit pointer jumping (3-barrier pattern).
// build_d: symmetric upper-triangle (R19-verified). Replay: R19 verbatim
// (Euler rooting -> ANSV -> S -> sort w/ fused tail -> segscan -> rank).

#define N 4096
#define DF 64
#define INF __builtin_huge_valf()

// ---------------------------------------------------------------------------
// Symmetric build_d + round-0 best. Grid = 2080 upper-triangle tiles.
// ---------------------------------------------------------------------------
__global__ __launch_bounds__(256) void build_d_kernel(const float* __restrict__ x,
                                                      float* __restrict__ D,
                                                      unsigned long long* __restrict__ best) {
    __shared__ float As[64][68];
    __shared__ float Bs[64][68];
    __shared__ float Ts[64][68];
    __shared__ unsigned long long colbuf[64][16];
    const int t = threadIdx.x;

    int br = 0;
    {
        int rem = blockIdx.x;
        while (rem >= 64 - br) {
            rem -= 64 - br;
            ++br;
        }
        int bc = br + rem;
        const int bi = br * 64;
        const int bj = bc * 64;

#pragma unroll
        for (int g = 0; g < 4; ++g) {
            int idx = t + 256 * g;
            int row = idx >> 4;
            int k4 = (idx & 15) << 2;
            *(float4*)(&As[row][k4]) =
                *(const float4*)(x + (size_t)(bi + row) * DF + k4);
            *(float4*)(&Bs[row][k4]) =
                *(const float4*)(x + (size_t)(bj + row) * DF + k4);
        }
        __syncthreads();

        const int ti = (t >> 4) << 2;
        const int tj = (t & 15) << 2;
        float acc[4][4];
#pragma unroll
        for (int r = 0; r < 4; ++r)
#pragma unroll
            for (int c = 0; c < 4; ++c) acc[r][c] = 0.0f;

        for (int k = 0; k < 64; k += 4) {
            float4 a[4], b[4];
#pragma unroll
            for (int r = 0; r < 4; ++r) a[r] = *(const float4*)(&As[ti + r][k]);
#pragma unroll
            for (int c = 0; c < 4; ++c) b[c] = *(const float4*)(&Bs[tj + c][k]);
#pragma unroll
            for (int r = 0; r < 4; ++r)
#pragma unroll
                for (int c = 0; c < 4; ++c) {
                    float d0 = a[r].x - b[c].x;
                    float d1 = a[r].y - b[c].y;
                    float d2 = a[r].z - b[c].z;
                    float d3 = a[r].w - b[c].w;
                    float s = acc[r][c];
                    s = fmaf(d0, d0, s);
                    s = fmaf(d1, d1, s);
                    s = fmaf(d2, d2, s);
                    s = fmaf(d3, d3, s);
                    acc[r][c] = s;
                }
        }

        float val[4][4];
#pragma unroll
        for (int r = 0; r < 4; ++r) {
            int i = bi + ti + r;
            float4 v;
            float* vp = &v.x;
            unsigned long long mk = ~0ULL;
#pragma unroll
            for (int c = 0; c < 4; ++c) {
                int j = bj + tj + c;
                float w = (i == j) ? INF : sqrtf(fmaxf(acc[r][c], 1e-12f));
                val[r][c] = w;
                vp[c] = w;
                unsigned long long key =
                    ((unsigned long long)__float_as_uint(w) << 24) |
                    ((unsigned long long)(unsigned)i << 12) | (unsigned)j;
                mk = key < mk ? key : mk;
            }
            *(float4*)(D + (size_t)i * N + (bj + tj)) = v;
#pragma unroll
            for (int m = 1; m < 16; m <<= 1) {
                unsigned long long o = __shfl_xor(mk, m, 64);
                mk = o < mk ? o : mk;
            }
            if ((t & 15) == 0) atomicMin(&best[i], mk);
        }

        if (br != bc) {
#pragma unroll
            for (int c = 0; c < 4; ++c) {
                unsigned long long ck = ~0ULL;
                int j = bj + tj + c;
#pragma unroll
                for (int r = 0; r < 4; ++r) {
                    int i = bi + ti + r;
                    float w = val[r][c];
                    Ts[tj + c][ti + r] = w;
                    unsigned long long key =
                        ((unsigned long long)__float_as_uint(w) << 24) |
                        ((unsigned long long)(unsigned)j << 12) | (unsigned)i;
                    ck = key < ck ? key : ck;
                }
                colbuf[tj + c][t >> 4] = ck;
            }
            __syncthreads();
            {
                int row = t >> 2;
                int seg = (t & 3) * 16;
                float4* dst = (float4*)(D + (size_t)(bj + row) * N + bi + seg);
#pragma unroll
                for (int q = 0; q < 4; ++q)
                    dst[q] = *(const float4*)(&Ts[row][seg + 4 * q]);
            }
            if (t < 64) {
                unsigned long long k = ~0ULL;
#pragma unroll
                for (int i2 = 0; i2 < 16; ++i2) {
                    unsigned long long v2 = colbuf[t][i2];
                    k = v2 < k ? v2 : k;
                }
                atomicMin(&best[bj + t], k);
            }
        }
    }
}

// ---------------------------------------------------------------------------
__global__ __launch_bounds__(256) void init_kernel(unsigned* comp,
                                                   unsigned long long* best,
                                                   unsigned* nedges, unsigned* done,
                                                   int nbuf) {
    int i = blockIdx.x * 256 + threadIdx.x;
    if (i < N) {
        comp[i] = (unsigned)i;
        for (int bb = 0; bb < nbuf; ++bb) best[(size_t)bb * N + i] = ~0ULL;
    }
    if (i == 0) { *nedges = 0u; *done = 0u; }
}

// ---------------------------------------------------------------------------
// Fused: local (redundant) merge of previous round + minedge scan.
// 256 blocks x 256 threads; no cross-block sync — determinism + kernel
// boundaries carry all state.
// ---------------------------------------------------------------------------
__global__ __launch_bounds__(256) void minedge_lm_kernel(
        const float* __restrict__ D, const unsigned* __restrict__ compi,
        unsigned* __restrict__ compo, unsigned long long* __restrict__ best,
        unsigned long long* edges, unsigned* nedges, unsigned* done, int rnd) {
    if (*done) return;
    __shared__ unsigned cl[N];
    __shared__ unsigned np[N];
    __shared__ unsigned long long keybuf[256];
    __shared__ unsigned cnt_sh, chg_sh;
    const int t = threadIdx.x;
    const int b = blockIdx.x;
    const unsigned long long* bcur = best + (size_t)((rnd - 1) % 3) * N;
    unsigned long long* bout = best + (size_t)(rnd % 3) * N;
    unsigned long long* brst = best + (size_t)((rnd + 1) % 3) * N;

    for (int v = t; v < N; v += 256) cl[v] = compi[v];
    if (t == 0) chg_sh = 0u;
    __syncthreads();

    // ---- hook ----
    unsigned long long kreg[16];
#pragma unroll
    for (int i = 0; i < 16; ++i) {
        int v = t + 256 * i;
        unsigned p;
        unsigned long long k = ~0ULL;
        if (cl[v] == (unsigned)v) {
            k = bcur[v];
            p = (k != ~0ULL) ? cl[(unsigned)(k & 0xFFFu)] : (unsigned)v;
        } else {
            p = cl[v];
        }
        np[v] = p;
        kreg[i] = k;
    }
    __syncthreads();
    // ---- 2-cycle resolve (all blocks identical); emit by block 0 only ----
#pragma unroll
    for (int i = 0; i < 16; ++i) {
        int v = t + 256 * i;
        if (cl[v] == (unsigned)v) {
            unsigned p = np[v];
            if (p != (unsigned)v) {
                bool mutual = (np[p] == (unsigned)v);
                if (mutual && (unsigned)v < p) {
                    np[v] = (unsigned)v;  // survivor root (benign race, R8)
                } else if (b == 0) {
                    unsigned idx = atomicAdd(nedges, 1u);
                    edges[idx] = kreg[i];
                }
            }
        }
    }
    __syncthreads();
    // ---- pointer jumping, chg-early-exit (3-barrier pattern) ----
    for (int it = 0; it < 12; ++it) {
        unsigned any = 0;
#pragma unroll
        for (int i = 0; i < 16; ++i) {
            int v = t + 256 * i;
            unsigned a = np[v];
            unsigned g = np[a];
            if (g != a) {
                np[v] = g;  // monotone; benign race (R8-verified)
                any = 1u;
            }
        }
        if (any) chg_sh = 1u;
        __syncthreads();
        unsigned fin = (chg_sh == 0u);
        __syncthreads();
        if (t == 0) chg_sh = 0u;
        __syncthreads();
        if (fin) break;
    }
    // ---- count roots; reset stale best buffer stripe ----
    if (t == 0) cnt_sh = 0u;
    __syncthreads();
    unsigned local = 0;
#pragma unroll
    for (int i = 0; i < 16; ++i) {
        int v = t + 256 * i;
        if (np[v] == (unsigned)v) ++local;
    }
    atomicAdd(&cnt_sh, local);
    if (t < 16) brst[b * 16 + t] = ~0ULL;
    __syncthreads();
    const bool finished = (cnt_sh == 1u);
    if (b == 0) {
        for (int v = t; v < N; v += 256) compo[v] = np[v];
        if (t == 0 && finished) *done = 1u;
    }
    if (finished) return;

    // ---- minedge scan (R16-verified shape), comp = np ----
    const int r = t >> 4;
    const int j = t & 15;
    const int rowv = b * 16 + r;
    const unsigned cr = np[rowv];
    const float4* rowp = (const float4*)(D + (size_t)rowv * N);
    unsigned long long mykey = ~0ULL;
#pragma unroll 4
    for (int k = 0; k < 64; ++k) {
        float4 v4 = rowp[j + 16 * k];
        int c0 = 4 * (j + 16 * k);
        const float* vp = &v4.x;
#pragma unroll
        for (int q = 0; q < 4; ++q) {
            int c = c0 + q;
            if (np[c] != cr) {
                unsigned long long key =
                    ((unsigned long long)__float_as_uint(vp[q]) << 24) |
                    ((unsigned long long)(unsigned)rowv << 12) | (unsigned)c;
                mykey = key < mykey ? key : mykey;
            }
        }
    }
    keybuf[t] = mykey;
    __syncthreads();
    if (t < 16) {
        unsigned long long k = ~0ULL;
#pragma unroll
        for (int i = 0; i < 16; ++i) {
            unsigned long long v2 = keybuf[t * 16 + i];
            k = v2 < k ? v2 : k;
        }
        if (k != ~0ULL) atomicMin(&bout[np[b * 16 + t]], k);
    }
}

// ---------------------------------------------------------------------------
// Recompute minedge (fallback path; R13-verified).
// ---------------------------------------------------------------------------
__global__ __launch_bounds__(256) void minedge_kernel(const float* __restrict__ x,
                                                      const unsigned* __restrict__ comp,
                                                      unsigned long long* __restrict__ best,
                                                      const unsigned* __restrict__ done) {
    if (*done) return;
    __shared__ float xr[16][64];
    __shared__ float xc[64][68];
    __shared__ unsigned compr[16];
    __shared__ unsigned compc[64];
    __shared__ unsigned long long keybuf[256];
    const int t = threadIdx.x;
    const int b = blockIdx.x;
    const int r = t >> 4;
    const int rowv = b * 16 + r;

    {
        int row = t >> 4, f4 = t & 15;
        *(float4*)&xr[row][f4 * 4] =
            *(const float4*)(x + (size_t)(b * 16 + row) * DF + f4 * 4);
        if (t < 16) compr[t] = comp[b * 16 + t];
    }
    __syncthreads();
    const unsigned cr = compr[r];
    unsigned long long mykey = ~0ULL;

    for (int tile = 0; tile < 64; ++tile) {
        {
#pragma unroll
            for (int q = 0; q < 4; ++q) {
                int idx = t + 256 * q;
                int col = idx >> 4, k4 = (idx & 15) * 4;
                *(float4*)&xc[col][k4] =
                    *(const float4*)(x + (size_t)(tile * 64 + col) * DF + k4);
            }
            if (t < 64) compc[t] = comp[tile * 64 + t];
        }
        __syncthreads();
#pragma unroll
        for (int q = 0; q < 4; ++q) {
            int c = (t & 15) + 16 * q;
            unsigned cc = compc[c];
            if (cc != cr) {
                float s = 0.0f;
#pragma unroll
                for (int k = 0; k < 64; k += 4) {
                    float4 a = *(const float4*)&xr[r][k];
                    float4 bb = *(const float4*)&xc[c][k];
                    float d0 = a.x - bb.x;
                    float d1 = a.y - bb.y;
                    float d2 = a.z - bb.z;
                    float d3 = a.w - bb.w;
                    s = fmaf(d0, d0, s);
                    s = fmaf(d1, d1, s);
                    s = fmaf(d2, d2, s);
                    s = fmaf(d3, d3, s);
                }
                float w = sqrtf(fmaxf(s, 1e-12f));
                unsigned long long key =
                    ((unsigned long long)__float_as_uint(w) << 24) |
                    ((unsigned long long)(unsigned)rowv << 12) |
                    (unsigned)(tile * 64 + c);
                mykey = key < mykey ? key : mykey;
            }
        }
        __syncthreads();
    }
    keybuf[t] = mykey;
    __syncthreads();
    if (t < 16) {
        unsigned long long k = ~0ULL;
#pragma unroll
        for (int i = 0; i < 16; ++i) {
            unsigned long long v2 = keybuf[t * 16 + i];
            k = v2 < k ? v2 : k;
        }
        if (k != ~0ULL) atomicMin(&best[compr[t]], k);
    }
}

// ---------------------------------------------------------------------------
// Boruvka merge (R14-verified; separate in/out comp pointers).
// ---------------------------------------------------------------------------
__global__ void merge_kernel(const unsigned* compi, unsigned* compo,
                             unsigned long long* best, unsigned long long* edges,
                             unsigned* nedges, unsigned* done) {
    if (*done) return;
    __shared__ unsigned cl[N];
    __shared__ unsigned np[N];
    __shared__ unsigned cnt;
    const int t = threadIdx.x;
    const int bs = blockDim.x;
    for (int v = t; v < N; v += bs) cl[v] = compi[v];
    __syncthreads();
    for (int v = t; v < N; v += bs) {
        unsigned p;
        if (cl[v] == (unsigned)v) {
            unsigned long long k = best[v];
            p = (k != ~0ULL) ? cl[(unsigned)(k & 0xFFFu)] : (unsigned)v;
        } else {
            p = cl[v];
        }
        np[v] = p;
    }
    __syncthreads();
    for (int v = t; v < N; v += bs) {
        if (cl[v] == (unsigned)v) {
            unsigned p = np[v];
            if (p != (unsigned)v) {
                bool mutual = (np[p] == (unsigned)v);
                if (mutual && (unsigned)v < p) {
                    np[v] = (unsigned)v;
                } else {
                    unsigned idx = atomicAdd(nedges, 1u);
                    edges[idx] = best[v];
                }
            }
        }
    }
    __syncthreads();
    for (int it = 0; it < 12; ++it) {
        for (int v = t; v < N; v += bs) np[v] = np[np[v]];
        __syncthreads();
    }
    if (t == 0) cnt = 0;
    __syncthreads();
    unsigned local = 0;
    for (int v = t; v < N; v += bs) {
        compo[v] = np[v];
        best[v] = ~0ULL;
        if (np[v] == (unsigned)v) ++local;
    }
    atomicAdd(&cnt, local);
    __syncthreads();
    if (t == 0 && cnt == 1u) *done = 1u;
}

// ---------------------------------------------------------------------------
// Replay (R19-verified): CSR(+twin) -> Euler-tour list-ranking -> ANSV ->
// S -> r-major sort (fused tail) -> segscan -> doubling -> scatter.
// ---------------------------------------------------------------------------
__global__ __launch_bounds__(1024) void replay_kernel(
        const unsigned long long* __restrict__ edges,
        const unsigned* __restrict__ nedges, float* __restrict__ out) {
    __shared__ __align__(16) unsigned char pool[156680];
    __shared__ unsigned chg;
    unsigned* off = (unsigned*)(pool + 65536);
    unsigned long long* ent = (unsigned long long*)(pool + 0);
    unsigned short* par = (unsigned short*)(pool + 81928);
    unsigned* keyw = (unsigned*)(pool + 90120);
    unsigned long long* key64 = (unsigned long long*)(pool + 0);
    unsigned long long* order = (unsigned long long*)(pool + 0);
    unsigned* ptr = (unsigned*)(pool + 106504);
    unsigned short* rankA = (unsigned short*)(pool + 106504);
    unsigned short* nxtA = (unsigned short*)(pool + 122888);
    unsigned short* twin = (unsigned short*)(pool + 139272);
    unsigned* Sa = (unsigned*)(pool + 32768);
    unsigned* Sb = (unsigned*)(pool + 49152);
    unsigned* T = (unsigned*)(pool + 65536);
    unsigned* vA = (unsigned*)(pool + 122888);
    unsigned* jA = (unsigned*)(pool + 139272);
    unsigned* vB = (unsigned*)(pool + 0);
    unsigned* jB = (unsigned*)(pool + 16384);
    unsigned* csum = (unsigned*)(pool + 155656);
    const int t = threadIdx.x;
    const unsigned ne = *nedges;
    const int ns = 2 * (int)ne;

    for (int v = t; v < N; v += 1024) off[v] = 0u;
    if (t == 0) off[N] = 0u;
    for (int k = t; k < N - 1; k += 1024) out[2 * k] = 0.0f;
    __syncthreads();
    for (int e = t; e < (int)ne; e += 1024) {
        unsigned long long k = edges[e];
        atomicAdd(&off[(unsigned)(k >> 12) & 0xFFFu], 1u);
        atomicAdd(&off[(unsigned)k & 0xFFFu], 1u);
    }
    __syncthreads();
    unsigned sloc = 0;
    unsigned loc[16];
    if (t < 256) {
        int base = t * 16;
#pragma unroll
        for (int i = 0; i < 16; ++i) {
            unsigned d = off[base + i];
            loc[i] = sloc;
            sloc += d;
        }
        csum[t] = sloc;
    }
    __syncthreads();
    for (int d = 1; d < 256; d <<= 1) {
        unsigned addv = 0;
        if (t < 256 && t >= d) addv = csum[t - d];
        __syncthreads();
        if (t < 256) csum[t] += addv;
        __syncthreads();
    }
    if (t < 256) {
        int base = t * 16;
        unsigned excl = csum[t] - sloc;
#pragma unroll
        for (int i = 0; i < 16; ++i) {
            unsigned o = loc[i] + excl;
            off[base + i] = o;
            keyw[base + i] = o;
        }
        if (t == 255) off[N] = csum[255];
    }
    __syncthreads();
    for (int e = t; e < (int)ne; e += 1024) {
        unsigned long long k = edges[e];
        unsigned a = (unsigned)(k >> 12) & 0xFFFu;
        unsigned b = (unsigned)k & 0xFFFu;
        unsigned long long wb = k >> 24;
        unsigned p1 = atomicAdd(&keyw[a], 1u);
        unsigned p2 = atomicAdd(&keyw[b], 1u);
        ent[p1] = (wb << 12) | b;
        ent[p2] = (wb << 12) | a;
        twin[p1] = (unsigned short)p2;
        twin[p2] = (unsigned short)p1;
    }
    __syncthreads();
    const unsigned s0 = off[0];
    for (int s = t; s < ns; s += 1024) {
        unsigned v = (unsigned)ent[s] & 0xFFFu;
        unsigned t2 = twin[s];
        unsigned nx = t2 + 1u;
        if (nx == off[v + 1]) nx = off[v];
        if (nx == s0) nx = 0xFFFFu;
        nxtA[s] = (unsigned short)nx;
        rankA[s] = 1;
    }
    __syncthreads();
    for (int round = 0; round < 13; ++round) {
        unsigned short rr[8], nn[8];
#pragma unroll
        for (int q = 0; q < 8; ++q) {
            int s = t + 1024 * q;
            rr[q] = 0;
            nn[q] = 0xFFFFu;
            if (s < ns) {
                unsigned n2 = nxtA[s];
                if (n2 != 0xFFFFu) {
                    rr[q] = rankA[n2];
                    nn[q] = nxtA[n2];
                }
            }
        }
        __syncthreads();
#pragma unroll
        for (int q = 0; q < 8; ++q) {
            int s = t + 1024 * q;
            if (s < ns && nxtA[s] != 0xFFFFu) {
                rankA[s] = (unsigned short)(rankA[s] + rr[q]);
                nxtA[s] = nn[q];
            }
        }
        __syncthreads();
    }
    for (int s = t; s < ns; s += 1024) {
        unsigned t2 = twin[s];
        if (rankA[s] > rankA[t2]) {
            unsigned v = (unsigned)ent[s] & 0xFFFu;
            par[v] = (unsigned short)((unsigned)ent[t2] & 0xFFFu);
            keyw[v] = (unsigned)(ent[s] >> 12);
        }
    }
    if (t == 0) {
        par[0] = 0;
        chg = 0u;
    }
    __syncthreads();
    for (int v = t; v < N; v += 1024) {
        key64[v] = (v == 0) ? ~0ULL
                            : (((unsigned long long)keyw[v]) << 24) |
                                  ((unsigned long long)par[v] << 12) | (unsigned)v;
    }
    __syncthreads();
    for (int v = t; v < N; v += 1024) ptr[v] = (v == 0) ? 0u : (unsigned)par[v];
    __syncthreads();
    for (;;) {
        for (int v = t; v < N; v += 1024) {
            unsigned p = ptr[v];
            if (key64[p] <= key64[v]) {
                unsigned q = ptr[p];
                if (q != p) {
                    ptr[v] = q;
                    chg = 1u;
                }
            }
        }
        __syncthreads();
        unsigned fin = (chg == 0u);
        __syncthreads();
        if (t == 0) chg = 0u;
        __syncthreads();
        if (fin) break;
    }
    unsigned* Sc = Sa;
    unsigned* Sn = Sb;
    for (int v = t; v < N; v += 1024) Sc[v] = 1u;
    __syncthreads();
    for (int round = 0; round < 64; ++round) {
        for (int v = t; v < N; v += 1024) Sn[v] = 1u;
        __syncthreads();
        for (int v = t; v < N; v += 1024)
            if (v != 0) atomicAdd(&Sn[ptr[v]], Sc[v]);
        __syncthreads();
        for (int v = t; v < N; v += 1024)
            if (Sn[v] != Sc[v]) chg = 1u;
        __syncthreads();
        unsigned fin = (chg == 0u);
        __syncthreads();
        if (t == 0) chg = 0u;
        __syncthreads();
        unsigned* tmp = Sc; Sc = Sn; Sn = tmp;
        if (fin) break;
    }
    for (int v = t; v < N; v += 1024) {
        order[v] = (v == 0)
                       ? (0xFFFFFull << 44)
                       : (((unsigned long long)ptr[v]) << 44) |
                             (((unsigned long long)keyw[v]) << 12) | (unsigned)v;
    }
    __syncthreads();
    for (unsigned k = 2; k <= 4096; k <<= 1) {
        for (unsigned j = k >> 1; j >= 4; j >>= 1) {
            for (unsigned i = t; i < 4096; i += 1024) {
                unsigned p = i ^ j;
                if (p > i) {
                    unsigned long long a = order[i], b = order[p];
                    bool up = ((i & k) == 0);
                    if ((a > b) == up) {
                        order[i] = b;
                        order[p] = a;
                    }
                }
            }
            __syncthreads();
        }
        {
            int base = 4 * t;
            unsigned long long e0 = order[base + 0];
            unsigned long long e1 = order[base + 1];
            unsigned long long e2 = order[base + 2];
            unsigned long long e3 = order[base + 3];
            if (k >= 4) {
                bool up = (((unsigned)base & k) == 0);
                unsigned long long tmp;
                if ((e0 > e2) == up) { tmp = e0; e0 = e2; e2 = tmp; }
                if ((e1 > e3) == up) { tmp = e1; e1 = e3; e3 = tmp; }
                if ((e0 > e1) == up) { tmp = e0; e0 = e1; e1 = tmp; }
                if ((e2 > e3) == up) { tmp = e2; e2 = e3; e3 = tmp; }
            } else {
                unsigned long long tmp;
                if (e0 > e1) { tmp = e0; e0 = e1; e1 = tmp; }
                if (e2 < e3) { tmp = e2; e2 = e3; e3 = tmp; }
            }
            order[base + 0] = e0;
            order[base + 1] = e1;
            order[base + 2] = e2;
            order[base + 3] = e3;
            __syncthreads();
        }
    }
    for (int i = t; i < 4096; i += 1024) {
        unsigned vv = (unsigned)order[i] & 0xFFFu;
        T[i] = Sc[vv];
    }
    __syncthreads();
    for (int d = 1; d < 4096; d <<= 1) {
        unsigned addv[4];
#pragma unroll
        for (int q = 0; q < 4; ++q) {
            int i = t + 1024 * q;
            addv[q] = 0;
            if (i >= d && (order[i] >> 44) == (order[i - d] >> 44)) addv[q] = T[i - d];
        }
        __syncthreads();
#pragma unroll
        for (int q = 0; q < 4; ++q) T[t + 1024 * q] += addv[q];
        __syncthreads();
    }
    for (int i = t; i < 4096; i += 1024) {
        unsigned vv = (unsigned)order[i] & 0xFFFu;
        if (vv) {
            vA[vv] = 1u + T[i] - Sc[vv];
            jA[vv] = ptr[vv];
        }
    }
    if (t == 0) {
        vA[0] = 0u;
        jA[0] = 0u;
    }
    __syncthreads();
    {
        unsigned *va = vA, *vb = vB, *ja = jA, *jb = jB;
        for (int r = 0; r < 12; ++r) {
            for (int v = t; v < N; v += 1024) {
                unsigned j2 = ja[v];
                vb[v] = va[v] + va[j2];
                jb[v] = ja[j2];
            }
            __syncthreads();
            unsigned* tmp;
            tmp = va; va = vb; vb = tmp;
            tmp = ja; ja = jb; jb = tmp;
        }
        for (int v = t; v < N; v += 1024) {
            if (v) out[2 * (va[v] - 1) + 1] = __uint_as_float(keyw[v]);
        }
    }
}

// ---------------------------------------------------------------------------
extern "C" void kernel_launch(void* const* d_in, const int* in_sizes, int n_in,
                              void* d_out, int out_size, void* d_ws, size_t ws_size,
                              hipStream_t stream) {
    const float* x = (const float*)d_in[0];
    float* out = (float*)d_out;  // [N-1][2]: (birth=0, death)
    const size_t dbytes = (size_t)N * N * 4;

    if (ws_size >= dbytes + 163840) {
        float* D = (float*)d_ws;
        unsigned char* st = (unsigned char*)d_ws + dbytes;
        unsigned long long* best = (unsigned long long*)st;              // 3*32768
        unsigned* comp0 = (unsigned*)(st + 98304);                       // 16 KB
        unsigned* comp1 = (unsigned*)(st + 114688);                      // 16 KB
        unsigned long long* edges = (unsigned long long*)(st + 131072);  // 32760 B
        unsigned* nedges = (unsigned*)(st + 163832);
        unsigned* done = (unsigned*)(st + 163836);

        init_kernel<<<16, 256, 0, stream>>>(comp0, best, nedges, done, 3);
        build_d_kernel<<<2080, 256, 0, stream>>>(x, D, best);  // -> best buf 0
        unsigned* cb[2] = {comp0, comp1};
        for (int r = 1; r <= 11; ++r) {
            minedge_lm_kernel<<<256, 256, 0, stream>>>(
                D, cb[(r - 1) & 1], cb[r & 1], best, edges, nedges, done, r);
        }
        // final (12th) merge: consumes best buf (12-1)%3 = 2
        merge_kernel<<<1, 1024, 0, stream>>>(cb[1], cb[0], best + (size_t)2 * N,
                                             edges, nedges, done);
        replay_kernel<<<1, 1024, 0, stream>>>(edges, nedges, out);
    } else {
        // Recompute fallback (R13-verified structure).
        unsigned char* ws = (unsigned char*)d_ws;
        unsigned* comp = (unsigned*)ws;                                  // 16 KB
        unsigned long long* best = (unsigned long long*)(ws + 16384);    // 32 KB
        unsigned long long* edges = (unsigned long long*)(ws + 49152);   // 32 KB
        unsigned* nedges = (unsigned*)(ws + 81920);
        unsigned* done = (unsigned*)(ws + 81984);

        init_kernel<<<16, 256, 0, stream>>>(comp, best, nedges, done, 1);
        for (int r = 0; r < 12; ++r) {
            minedge_kernel<<<256, 256, 0, stream>>>(x, comp, best, done);
            merge_kernel<<<1, 1024, 0, stream>>>(comp, comp, best, edges, nedges,
                                                 done);
        }
        replay_kernel<<<1, 1024, 0, stream>>>(edges, nedges, out);
    }
}